// Round 1
// baseline (2423.482 us; speedup 1.0000x reference)
//
#include <hip/hip_runtime.h>
#include <hip/hip_bf16.h>

// Problem constants (match reference)
#define NN 50000   // nodes
#define NE 150000  // edges
#define NR 65      // relations
#define NG 2000    // graphs
#define FIN 74     // input features
#define HD 256     // hidden
#define MH 64      // mlp hidden

// GEMM tiling
#define TE 64      // rows (edges/nodes) per tile
#define TN 128     // output cols per tile
#define TK 32      // k-chunk
#define MAX_TILES 40  // edge tiles per relation per pass (loop covers overflow)

// ---------------------------------------------------------------------------
// Edge preprocessing: count per (dst,rel), histogram per rel, counting sort.
// ---------------------------------------------------------------------------
__global__ void count_k(const int* __restrict__ dst, const int* __restrict__ et,
                        int* __restrict__ cnt, int* __restrict__ hist) {
  int e = blockIdx.x * 256 + threadIdx.x;
  if (e < NE) {
    int r = et[e];
    atomicAdd(&cnt[(size_t)dst[e] * NR + r], 1);
    atomicAdd(&hist[r], 1);
  }
}

__global__ void prefix_k(const int* __restrict__ hist, int* __restrict__ offr) {
  if (threadIdx.x == 0) {
    int s = 0;
    for (int r = 0; r < NR; ++r) { offr[r] = s; s += hist[r]; }
    offr[NR] = s;
  }
}

__global__ void scatter_k(const int* __restrict__ src, const int* __restrict__ dst,
                          const int* __restrict__ et, const int* __restrict__ cnt,
                          const int* __restrict__ offr, int* __restrict__ cur,
                          int* __restrict__ es, int* __restrict__ ed,
                          float* __restrict__ enorm) {
  int e = blockIdx.x * 256 + threadIdx.x;
  if (e < NE) {
    int r = et[e];
    int d = dst[e];
    int p = offr[r] + atomicAdd(&cur[r], 1);
    es[p] = src[e];
    ed[p] = d;
    int c = cnt[(size_t)d * NR + r];
    enorm[p] = 1.0f / (float)(c > 0 ? c : 1);
  }
}

// ---------------------------------------------------------------------------
// Dense root GEMM: out[M][256] = X[M][K] @ W[K][256] + bias
// 256 threads, 64x128 tile, 8x4 register blocking.
// ---------------------------------------------------------------------------
template<int K>
__global__ __launch_bounds__(256) void gemm_root(const float* __restrict__ X,
                                                 const float* __restrict__ W,
                                                 const float* __restrict__ bias,
                                                 float* __restrict__ out, int M) {
  __shared__ float xs[TK][TE + 1];  // [kk][row], +1 pad -> conflict-free writes
  __shared__ float ws[TK][TN];
  const int t = threadIdx.x;
  const int row0 = blockIdx.x * TE;
  const int col0 = blockIdx.y * TN;
  const int tcol = t & 31;   // 32 groups x 4 cols
  const int trow = t >> 5;   // 8 groups x 8 rows
  const int kk_x = t & 31;   // X loader: k index
  const int rr_x = t >> 5;   // X loader: row group

  float acc[8][4] = {};
  for (int k0 = 0; k0 < K; k0 += TK) {
    // X tile: lanes 0..31 read consecutive k of one row (coalesced)
#pragma unroll
    for (int i = 0; i < TE / 8; ++i) {
      int row = rr_x * 8 + i;
      int gr = row0 + row, gk = k0 + kk_x;
      float v = 0.f;
      if (gr < M && gk < K) v = X[(size_t)gr * K + gk];
      xs[kk_x][row] = v;
    }
    // W tile: float4, coalesced
#pragma unroll
    for (int i = 0; i < 4; ++i) {
      int kk = (t >> 5) + i * 8;
      int c4 = t & 31;
      float4 v = make_float4(0.f, 0.f, 0.f, 0.f);
      int gk = k0 + kk;
      if (gk < K) v = *(const float4*)&W[(size_t)gk * HD + col0 + c4 * 4];
      *(float4*)&ws[kk][c4 * 4] = v;
    }
    __syncthreads();
#pragma unroll
    for (int kk = 0; kk < TK; ++kk) {
      float4 wv = *(const float4*)&ws[kk][tcol * 4];
      float xv[8];
#pragma unroll
      for (int i = 0; i < 8; ++i) xv[i] = xs[kk][trow * 8 + i];
#pragma unroll
      for (int i = 0; i < 8; ++i) {
        acc[i][0] += xv[i] * wv.x;
        acc[i][1] += xv[i] * wv.y;
        acc[i][2] += xv[i] * wv.z;
        acc[i][3] += xv[i] * wv.w;
      }
    }
    __syncthreads();
  }
  float4 bv = *(const float4*)&bias[col0 + tcol * 4];
#pragma unroll
  for (int i = 0; i < 8; ++i) {
    int gr = row0 + trow * 8 + i;
    if (gr < M) {
      float4 o;
      o.x = acc[i][0] + bv.x;
      o.y = acc[i][1] + bv.y;
      o.z = acc[i][2] + bv.z;
      o.w = acc[i][3] + bv.w;
      *(float4*)&out[(size_t)gr * HD + col0 + tcol * 4] = o;
    }
  }
}

// ---------------------------------------------------------------------------
// Edge-batched segmented GEMM: for each edge e (sorted by relation),
//   out[dst_e] += (norm_e * X[src_e]) @ W[rel_e]     (atomicAdd scatter)
// Block = (relation, tile-in-relation, col-half). Tiles of 64 edges share W[r].
// ---------------------------------------------------------------------------
template<int K>
__global__ __launch_bounds__(256) void gemm_edge(const float* __restrict__ X,
                                                 const float* __restrict__ Wall,
                                                 const int* __restrict__ es,
                                                 const int* __restrict__ ed,
                                                 const float* __restrict__ enorm,
                                                 const int* __restrict__ offr,
                                                 float* __restrict__ out) {
  __shared__ float xs[TK][TE + 1];
  __shared__ float ws[TK][TN];
  const int t = threadIdx.x;
  const int rel = blockIdx.x / MAX_TILES;
  const int tile = blockIdx.x % MAX_TILES;
  const int col0 = blockIdx.y * TN;
  const int e_lo = offr[rel], e_hi = offr[rel + 1];
  const float* W = Wall + (size_t)rel * K * HD;
  const int tcol = t & 31;
  const int trow = t >> 5;
  const int kk_x = t & 31;
  const int rr_x = t >> 5;

  for (int base = e_lo + tile * TE; base < e_hi; base += MAX_TILES * TE) {
    const int nE = min(TE, e_hi - base);
    float acc[8][4] = {};
    for (int k0 = 0; k0 < K; k0 += TK) {
#pragma unroll
      for (int i = 0; i < TE / 8; ++i) {
        int row = rr_x * 8 + i;
        int gk = k0 + kk_x;
        float v = 0.f;
        if (row < nE && gk < K) {
          int s = es[base + row];
          v = X[(size_t)s * K + gk] * enorm[base + row];
        }
        xs[kk_x][row] = v;
      }
#pragma unroll
      for (int i = 0; i < 4; ++i) {
        int kk = (t >> 5) + i * 8;
        int c4 = t & 31;
        float4 v = make_float4(0.f, 0.f, 0.f, 0.f);
        int gk = k0 + kk;
        if (gk < K) v = *(const float4*)&W[(size_t)gk * HD + col0 + c4 * 4];
        *(float4*)&ws[kk][c4 * 4] = v;
      }
      __syncthreads();
#pragma unroll
      for (int kk = 0; kk < TK; ++kk) {
        float4 wv = *(const float4*)&ws[kk][tcol * 4];
        float xv[8];
#pragma unroll
        for (int i = 0; i < 8; ++i) xv[i] = xs[kk][trow * 8 + i];
#pragma unroll
        for (int i = 0; i < 8; ++i) {
          acc[i][0] += xv[i] * wv.x;
          acc[i][1] += xv[i] * wv.y;
          acc[i][2] += xv[i] * wv.z;
          acc[i][3] += xv[i] * wv.w;
        }
      }
      __syncthreads();
    }
    // scatter
#pragma unroll
    for (int i = 0; i < 8; ++i) {
      int row = trow * 8 + i;
      if (row < nE) {
        int d = ed[base + row];
        float* o = &out[(size_t)d * HD + col0 + tcol * 4];
        atomicAdd(o + 0, acc[i][0]);
        atomicAdd(o + 1, acc[i][1]);
        atomicAdd(o + 2, acc[i][2]);
        atomicAdd(o + 3, acc[i][3]);
      }
    }
  }
}

__global__ void relu_k(float* __restrict__ p, int n4) {
  int i = blockIdx.x * 256 + threadIdx.x;
  if (i < n4) {
    float4 v = *(float4*)&p[i * 4];
    v.x = fmaxf(v.x, 0.f);
    v.y = fmaxf(v.y, 0.f);
    v.z = fmaxf(v.z, 0.f);
    v.w = fmaxf(v.w, 0.f);
    *(float4*)&p[i * 4] = v;
  }
}

// One wave per node: gate = sigmoid(h . ws_w + ws_b); g[batch[n]] += gate * h
__global__ __launch_bounds__(256) void pool_k(const float* __restrict__ h,
                                              const float* __restrict__ wsw,
                                              const float* __restrict__ wsb,
                                              const int* __restrict__ batch,
                                              float* __restrict__ g) {
  int gtid = blockIdx.x * 256 + threadIdx.x;
  int node = gtid >> 6;
  int lane = threadIdx.x & 63;
  if (node >= NN) return;
  const float* row = h + (size_t)node * HD;
  float4 v = *(const float4*)&row[lane * 4];
  float4 w4 = *(const float4*)&wsw[lane * 4];
  float p = v.x * w4.x + v.y * w4.y + v.z * w4.z + v.w * w4.w;
#pragma unroll
  for (int o = 32; o > 0; o >>= 1) p += __shfl_xor(p, o, 64);
  float gate = 1.f / (1.f + expf(-(p + wsb[0])));
  int b = batch[node];
  float* gr = g + (size_t)b * HD;
  atomicAdd(&gr[lane * 4 + 0], gate * v.x);
  atomicAdd(&gr[lane * 4 + 1], gate * v.y);
  atomicAdd(&gr[lane * 4 + 2], gate * v.z);
  atomicAdd(&gr[lane * 4 + 3], gate * v.w);
}

// Fused MLP head: one wave per graph. 256 -> 64 -> 64 -> 1
__global__ __launch_bounds__(64) void mlp_k(const float* __restrict__ g,
                                            const float* __restrict__ m1,
                                            const float* __restrict__ mb1,
                                            const float* __restrict__ m2,
                                            const float* __restrict__ mb2,
                                            const float* __restrict__ m3,
                                            const float* __restrict__ mb3,
                                            float* __restrict__ out) {
  __shared__ float sg[HD];
  __shared__ float s1[MH];
  int gr = blockIdx.x;
  int t = threadIdx.x;
  float4 v = *(const float4*)&g[(size_t)gr * HD + t * 4];
  *(float4*)&sg[t * 4] = v;
  __syncthreads();
  float a = mb1[t];
  for (int k = 0; k < HD; ++k) a += sg[k] * m1[k * MH + t];
  a = fmaxf(a, 0.f);
  s1[t] = a;
  __syncthreads();
  float b = mb2[t];
#pragma unroll
  for (int k = 0; k < MH; ++k) b += s1[k] * m2[k * MH + t];
  b = fmaxf(b, 0.f);
  float c = b * m3[t];
#pragma unroll
  for (int o = 32; o > 0; o >>= 1) c += __shfl_xor(c, o, 64);
  if (t == 0) out[gr] = c + mb3[0];
}

// ---------------------------------------------------------------------------
extern "C" void kernel_launch(void* const* d_in, const int* in_sizes, int n_in,
                              void* d_out, int out_size, void* d_ws, size_t ws_size,
                              hipStream_t stream) {
  const float* x = (const float*)d_in[0];
  const int* ei = (const int*)d_in[1];
  const int* etype = (const int*)d_in[2];
  const int* batch = (const int*)d_in[3];
  const float* W1 = (const float*)d_in[4];
  const float* root1 = (const float*)d_in[5];
  const float* b1 = (const float*)d_in[6];
  const float* W2 = (const float*)d_in[7];
  const float* root2 = (const float*)d_in[8];
  const float* b2 = (const float*)d_in[9];
  const float* wsw = (const float*)d_in[10];
  const float* wsb = (const float*)d_in[11];
  const float* m1 = (const float*)d_in[12];
  const float* mb1 = (const float*)d_in[13];
  const float* m2 = (const float*)d_in[14];
  const float* mb2 = (const float*)d_in[15];
  const float* m3 = (const float*)d_in[16];
  const float* mb3 = (const float*)d_in[17];
  const int* esrc = ei;
  const int* edst = ei + NE;

  // Workspace layout (256B aligned). Zeroed region first: [cnt|hist|cur|g].
  char* ws = (char*)d_ws;
  size_t off = 0;
  auto alloc = [&](size_t bytes) {
    size_t o = off;
    off = (off + bytes + 255) & ~(size_t)255;
    return o;
  };
  size_t o_cnt = alloc((size_t)NN * NR * 4);
  size_t o_hist = alloc(NR * 4);
  size_t o_cur = alloc(NR * 4);
  size_t o_g = alloc((size_t)NG * HD * 4);
  size_t zend = off;  // zero [0, zend)
  size_t o_off = alloc((NR + 1) * 4);
  size_t o_es = alloc((size_t)NE * 4);
  size_t o_ed = alloc((size_t)NE * 4);
  size_t o_enorm = alloc((size_t)NE * 4);
  size_t o_h1 = alloc((size_t)NN * HD * 4);
  size_t o_h2 = alloc((size_t)NN * HD * 4);
  if (ws_size < off) return;  // insufficient scratch; avoid corruption

  int* cnt = (int*)(ws + o_cnt);
  int* hist = (int*)(ws + o_hist);
  int* cur = (int*)(ws + o_cur);
  float* g = (float*)(ws + o_g);
  int* offr = (int*)(ws + o_off);
  int* es = (int*)(ws + o_es);
  int* ed = (int*)(ws + o_ed);
  float* enorm = (float*)(ws + o_enorm);
  float* h1 = (float*)(ws + o_h1);
  float* h2 = (float*)(ws + o_h2);
  float* outp = (float*)d_out;

  hipMemsetAsync(ws, 0, zend, stream);

  count_k<<<(NE + 255) / 256, 256, 0, stream>>>(edst, etype, cnt, hist);
  prefix_k<<<1, 64, 0, stream>>>(hist, offr);
  scatter_k<<<(NE + 255) / 256, 256, 0, stream>>>(esrc, edst, etype, cnt, offr,
                                                  cur, es, ed, enorm);

  dim3 gRoot((NN + TE - 1) / TE, HD / TN);
  dim3 gEdge(NR * MAX_TILES, HD / TN);

  // Layer 1
  gemm_root<FIN><<<gRoot, 256, 0, stream>>>(x, root1, b1, h1, NN);
  gemm_edge<FIN><<<gEdge, 256, 0, stream>>>(x, W1, es, ed, enorm, offr, h1);
  relu_k<<<(NN * HD / 4 + 255) / 256, 256, 0, stream>>>(h1, NN * HD / 4);

  // Layer 2
  gemm_root<HD><<<gRoot, 256, 0, stream>>>(h1, root2, b2, h2, NN);
  gemm_edge<HD><<<gEdge, 256, 0, stream>>>(h1, W2, es, ed, enorm, offr, h2);
  relu_k<<<(NN * HD / 4 + 255) / 256, 256, 0, stream>>>(h2, NN * HD / 4);

  // Pooling + MLP head
  pool_k<<<(NN * 64 + 255) / 256, 256, 0, stream>>>(h2, wsw, wsb, batch, g);
  mlp_k<<<NG, 64, 0, stream>>>(g, m1, mb1, m2, mb2, m3, mb3, outp);
}

// Round 2
// 1581.138 us; speedup vs baseline: 1.5327x; 1.5327x over previous
//
#include <hip/hip_runtime.h>
#include <hip/hip_bf16.h>

// Problem constants (match reference)
#define NN 50000   // nodes
#define NE 150000  // edges
#define NR 65      // relations
#define NG 2000    // graphs
#define FIN 74     // input features
#define HD 256     // hidden
#define MH 64      // mlp hidden

// GEMM tiling
#define TE 64      // rows (edges/nodes) per tile
#define TN 128     // output cols per tile
#define TK 32      // k-chunk
#define MAX_TILES 40  // edge tiles per relation per pass (loop covers overflow)

// ---------------------------------------------------------------------------
// Edge preprocessing
// ---------------------------------------------------------------------------
__global__ void count_k(const int* __restrict__ dst, const int* __restrict__ et,
                        int* __restrict__ cnt, int* __restrict__ hist,
                        int* __restrict__ ndeg) {
  __shared__ int lh[NR];
  int t = threadIdx.x;
  if (t < NR) lh[t] = 0;
  __syncthreads();
  int e = blockIdx.x * 256 + t;
  if (e < NE) {
    int r = et[e], d = dst[e];
    atomicAdd(&cnt[(size_t)d * NR + r], 1);
    atomicAdd(&lh[r], 1);
    atomicAdd(&ndeg[d], 1);
  }
  __syncthreads();
  if (t < NR && lh[t]) atomicAdd(&hist[t], lh[t]);
}

__global__ void gcount_k(const int* __restrict__ batch, int* __restrict__ ghist) {
  int i = blockIdx.x * 256 + threadIdx.x;
  if (i < NN) atomicAdd(&ghist[batch[i]], 1);
}

// Single-block exclusive scan: out[i] = sum(in[0..i-1]), out[n] = total.
__global__ void scan_k(const int* __restrict__ in, int* __restrict__ out, int n) {
  __shared__ int ssum[256];
  int t = threadIdx.x;
  int chunk = (n + 255) / 256;
  int lo = t * chunk;
  int hi = lo + chunk; if (hi > n) hi = n;
  int s = 0;
  for (int i = lo; i < hi; ++i) s += in[i];
  ssum[t] = s;
  __syncthreads();
  if (t == 0) {
    int acc = 0;
    for (int i = 0; i < 256; ++i) { int v = ssum[i]; ssum[i] = acc; acc += v; }
  }
  __syncthreads();
  int acc = ssum[t];
  for (int i = lo; i < hi; ++i) { out[i] = acc; acc += in[i]; }
  if (hi == n && lo <= n) out[n] = acc;
}

// Counting-sort edges by relation; materialize norm = 1/cnt(dst,rel).
__global__ void scatter_k(const int* __restrict__ src, const int* __restrict__ dst,
                          const int* __restrict__ et, const int* __restrict__ cnt,
                          const int* __restrict__ offr, int* __restrict__ cur,
                          int* __restrict__ es, int* __restrict__ ed,
                          float* __restrict__ enorm) {
  int e = blockIdx.x * 256 + threadIdx.x;
  if (e < NE) {
    int r = et[e];
    int d = dst[e];
    int p = offr[r] + atomicAdd(&cur[r], 1);
    es[p] = src[e];
    ed[p] = d;
    int c = cnt[(size_t)d * NR + r];
    enorm[p] = 1.0f / (float)(c > 0 ? c : 1);
  }
}

// Sort edge positions p by dst into CSR (nodeoff, plist).
__global__ void plist_k(const int* __restrict__ ed, const int* __restrict__ nodeoff,
                        int* __restrict__ ncur, int* __restrict__ plist) {
  int p = blockIdx.x * 256 + threadIdx.x;
  if (p < NE) {
    int d = ed[p];
    int q = nodeoff[d] + atomicAdd(&ncur[d], 1);
    plist[q] = p;
  }
}

// ---------------------------------------------------------------------------
// Dense root GEMM: out[M][256] = X[M][K] @ W[K][256] + bias
// ---------------------------------------------------------------------------
template<int K>
__global__ __launch_bounds__(256) void gemm_root(const float* __restrict__ X,
                                                 const float* __restrict__ W,
                                                 const float* __restrict__ bias,
                                                 float* __restrict__ out, int M) {
  __shared__ float xs[TK][TE + 1];
  __shared__ float ws[TK][TN];
  const int t = threadIdx.x;
  const int row0 = blockIdx.x * TE;
  const int col0 = blockIdx.y * TN;
  const int tcol = t & 31;
  const int trow = t >> 5;
  const int kk_x = t & 31;
  const int rr_x = t >> 5;

  float acc[8][4] = {};
  for (int k0 = 0; k0 < K; k0 += TK) {
#pragma unroll
    for (int i = 0; i < TE / 8; ++i) {
      int row = rr_x * 8 + i;
      int gr = row0 + row, gk = k0 + kk_x;
      float v = 0.f;
      if (gr < M && gk < K) v = X[(size_t)gr * K + gk];
      xs[kk_x][row] = v;
    }
#pragma unroll
    for (int i = 0; i < 4; ++i) {
      int kk = (t >> 5) + i * 8;
      int c4 = t & 31;
      float4 v = make_float4(0.f, 0.f, 0.f, 0.f);
      int gk = k0 + kk;
      if (gk < K) v = *(const float4*)&W[(size_t)gk * HD + col0 + c4 * 4];
      *(float4*)&ws[kk][c4 * 4] = v;
    }
    __syncthreads();
#pragma unroll
    for (int kk = 0; kk < TK; ++kk) {
      float4 wv = *(const float4*)&ws[kk][tcol * 4];
      float xv[8];
#pragma unroll
      for (int i = 0; i < 8; ++i) xv[i] = xs[kk][trow * 8 + i];
#pragma unroll
      for (int i = 0; i < 8; ++i) {
        acc[i][0] += xv[i] * wv.x;
        acc[i][1] += xv[i] * wv.y;
        acc[i][2] += xv[i] * wv.z;
        acc[i][3] += xv[i] * wv.w;
      }
    }
    __syncthreads();
  }
  float4 bv = *(const float4*)&bias[col0 + tcol * 4];
#pragma unroll
  for (int i = 0; i < 8; ++i) {
    int gr = row0 + trow * 8 + i;
    if (gr < M) {
      float4 o;
      o.x = acc[i][0] + bv.x;
      o.y = acc[i][1] + bv.y;
      o.z = acc[i][2] + bv.z;
      o.w = acc[i][3] + bv.w;
      *(float4*)&out[(size_t)gr * HD + col0 + tcol * 4] = o;
    }
  }
}

// ---------------------------------------------------------------------------
// Edge-batched segmented GEMM (rel-sorted). Writes per-edge rows to tmp —
// plain coalesced stores, NO atomics.
//   tmp[p] = (norm_p * X[es[p]]) @ W[rel(p)]
// ---------------------------------------------------------------------------
template<int K>
__global__ __launch_bounds__(256) void gemm_edge(const float* __restrict__ X,
                                                 const float* __restrict__ Wall,
                                                 const int* __restrict__ es,
                                                 const float* __restrict__ enorm,
                                                 const int* __restrict__ offr,
                                                 float* __restrict__ tmp) {
  __shared__ float xs[TK][TE + 1];
  __shared__ float ws[TK][TN];
  const int t = threadIdx.x;
  const int rel = blockIdx.x / MAX_TILES;
  const int tile = blockIdx.x % MAX_TILES;
  const int col0 = blockIdx.y * TN;
  const int e_lo = offr[rel], e_hi = offr[rel + 1];
  const float* W = Wall + (size_t)rel * K * HD;
  const int tcol = t & 31;
  const int trow = t >> 5;
  const int kk_x = t & 31;
  const int rr_x = t >> 5;

  for (int base = e_lo + tile * TE; base < e_hi; base += MAX_TILES * TE) {
    const int nE = min(TE, e_hi - base);
    float acc[8][4] = {};
    for (int k0 = 0; k0 < K; k0 += TK) {
#pragma unroll
      for (int i = 0; i < TE / 8; ++i) {
        int row = rr_x * 8 + i;
        int gk = k0 + kk_x;
        float v = 0.f;
        if (row < nE && gk < K) {
          int s = es[base + row];
          v = X[(size_t)s * K + gk] * enorm[base + row];
        }
        xs[kk_x][row] = v;
      }
#pragma unroll
      for (int i = 0; i < 4; ++i) {
        int kk = (t >> 5) + i * 8;
        int c4 = t & 31;
        float4 v = make_float4(0.f, 0.f, 0.f, 0.f);
        int gk = k0 + kk;
        if (gk < K) v = *(const float4*)&W[(size_t)gk * HD + col0 + c4 * 4];
        *(float4*)&ws[kk][c4 * 4] = v;
      }
      __syncthreads();
#pragma unroll
      for (int kk = 0; kk < TK; ++kk) {
        float4 wv = *(const float4*)&ws[kk][tcol * 4];
        float xv[8];
#pragma unroll
        for (int i = 0; i < 8; ++i) xv[i] = xs[kk][trow * 8 + i];
#pragma unroll
        for (int i = 0; i < 8; ++i) {
          acc[i][0] += xv[i] * wv.x;
          acc[i][1] += xv[i] * wv.y;
          acc[i][2] += xv[i] * wv.z;
          acc[i][3] += xv[i] * wv.w;
        }
      }
      __syncthreads();
    }
#pragma unroll
    for (int i = 0; i < 8; ++i) {
      int row = trow * 8 + i;
      if (row < nE) {
        float4 o;
        o.x = acc[i][0]; o.y = acc[i][1]; o.z = acc[i][2]; o.w = acc[i][3];
        *(float4*)&tmp[(size_t)(base + row) * HD + col0 + tcol * 4] = o;
      }
    }
  }
}

// ---------------------------------------------------------------------------
// Per-node gather-reduce: h[n] = relu(h[n] + sum_{p in CSR[n]} tmp[p]).
// One wave per node, float4 per lane. In-place, no atomics.
// ---------------------------------------------------------------------------
__global__ __launch_bounds__(256) void reduce_k(float* __restrict__ h,
                                                const float* __restrict__ tmp,
                                                const int* __restrict__ nodeoff,
                                                const int* __restrict__ plist) {
  int wid = (blockIdx.x * 256 + threadIdx.x) >> 6;
  int lane = threadIdx.x & 63;
  if (wid >= NN) return;
  float* row = h + (size_t)wid * HD + lane * 4;
  float4 acc = *(float4*)row;
  int lo = nodeoff[wid], hi = nodeoff[wid + 1];
  for (int q = lo; q < hi; ++q) {
    int p = plist[q];
    float4 v = *(const float4*)&tmp[(size_t)p * HD + lane * 4];
    acc.x += v.x; acc.y += v.y; acc.z += v.z; acc.w += v.w;
  }
  acc.x = fmaxf(acc.x, 0.f);
  acc.y = fmaxf(acc.y, 0.f);
  acc.z = fmaxf(acc.z, 0.f);
  acc.w = fmaxf(acc.w, 0.f);
  *(float4*)row = acc;
}

// ---------------------------------------------------------------------------
// Pooling: batch is sorted -> per-graph contiguous node range. One wave per
// graph, register accumulation, non-atomic store.
// ---------------------------------------------------------------------------
__global__ __launch_bounds__(256) void pool_k(const float* __restrict__ h,
                                              const float* __restrict__ wsw,
                                              const float* __restrict__ wsb,
                                              const int* __restrict__ goff,
                                              float* __restrict__ g) {
  int wid = (blockIdx.x * 256 + threadIdx.x) >> 6;
  int lane = threadIdx.x & 63;
  if (wid >= NG) return;
  float4 w4 = *(const float4*)&wsw[lane * 4];
  float wb = wsb[0];
  float4 acc = make_float4(0.f, 0.f, 0.f, 0.f);
  int lo = goff[wid], hi = goff[wid + 1];
  for (int n = lo; n < hi; ++n) {
    float4 v = *(const float4*)&h[(size_t)n * HD + lane * 4];
    float p = v.x * w4.x + v.y * w4.y + v.z * w4.z + v.w * w4.w;
#pragma unroll
    for (int o = 32; o > 0; o >>= 1) p += __shfl_xor(p, o, 64);
    float gate = 1.f / (1.f + expf(-(p + wb)));
    acc.x += gate * v.x;
    acc.y += gate * v.y;
    acc.z += gate * v.z;
    acc.w += gate * v.w;
  }
  *(float4*)&g[(size_t)wid * HD + lane * 4] = acc;
}

// Fused MLP head: one wave per graph. 256 -> 64 -> 64 -> 1
__global__ __launch_bounds__(64) void mlp_k(const float* __restrict__ g,
                                            const float* __restrict__ m1,
                                            const float* __restrict__ mb1,
                                            const float* __restrict__ m2,
                                            const float* __restrict__ mb2,
                                            const float* __restrict__ m3,
                                            const float* __restrict__ mb3,
                                            float* __restrict__ out) {
  __shared__ float sg[HD];
  __shared__ float s1[MH];
  int gr = blockIdx.x;
  int t = threadIdx.x;
  float4 v = *(const float4*)&g[(size_t)gr * HD + t * 4];
  *(float4*)&sg[t * 4] = v;
  __syncthreads();
  float a = mb1[t];
  for (int k = 0; k < HD; ++k) a += sg[k] * m1[k * MH + t];
  a = fmaxf(a, 0.f);
  s1[t] = a;
  __syncthreads();
  float b = mb2[t];
#pragma unroll
  for (int k = 0; k < MH; ++k) b += s1[k] * m2[k * MH + t];
  b = fmaxf(b, 0.f);
  float c = b * m3[t];
#pragma unroll
  for (int o = 32; o > 0; o >>= 1) c += __shfl_xor(c, o, 64);
  if (t == 0) out[gr] = c + mb3[0];
}

// ---------------------------------------------------------------------------
extern "C" void kernel_launch(void* const* d_in, const int* in_sizes, int n_in,
                              void* d_out, int out_size, void* d_ws, size_t ws_size,
                              hipStream_t stream) {
  const float* x = (const float*)d_in[0];
  const int* ei = (const int*)d_in[1];
  const int* etype = (const int*)d_in[2];
  const int* batch = (const int*)d_in[3];
  const float* W1 = (const float*)d_in[4];
  const float* root1 = (const float*)d_in[5];
  const float* b1 = (const float*)d_in[6];
  const float* W2 = (const float*)d_in[7];
  const float* root2 = (const float*)d_in[8];
  const float* b2 = (const float*)d_in[9];
  const float* wsw = (const float*)d_in[10];
  const float* wsb = (const float*)d_in[11];
  const float* m1 = (const float*)d_in[12];
  const float* mb1 = (const float*)d_in[13];
  const float* m2 = (const float*)d_in[14];
  const float* mb2 = (const float*)d_in[15];
  const float* m3 = (const float*)d_in[16];
  const float* mb3 = (const float*)d_in[17];
  const int* esrc = ei;
  const int* edst = ei + NE;

  // Workspace layout (256B aligned).
  char* ws = (char*)d_ws;
  size_t off = 0;
  auto alloc = [&](size_t bytes) {
    size_t o = off;
    off = (off + bytes + 255) & ~(size_t)255;
    return o;
  };
  size_t o_tmp = alloc((size_t)NE * HD * 4);   // 153.6 MB; cnt aliased at front
  size_t o_h1 = alloc((size_t)NN * HD * 4);    // 51.2 MB
  size_t o_h2 = alloc((size_t)NN * HD * 4);    // 51.2 MB
  size_t o_g = alloc((size_t)NG * HD * 4);     // 2.05 MB
  size_t o_es = alloc((size_t)NE * 4);
  size_t o_ed = alloc((size_t)NE * 4);
  size_t o_enorm = alloc((size_t)NE * 4);
  size_t o_plist = alloc((size_t)NE * 4);
  size_t o_nodeoff = alloc((NN + 1) * 4);
  size_t o_goff = alloc((NG + 1) * 4);
  size_t o_offr = alloc((NR + 1) * 4);
  size_t zs = off;                              // zero region start
  size_t o_hist = alloc(NR * 4);
  size_t o_cur = alloc(NR * 4);
  size_t o_ndeg = alloc((size_t)NN * 4);
  size_t o_ncur = alloc((size_t)NN * 4);
  size_t o_ghist = alloc((size_t)NG * 4);
  size_t ze = off;
  if (ws_size < off) return;  // insufficient scratch

  float* tmp = (float*)(ws + o_tmp);
  int* cnt = (int*)(ws + o_tmp);  // alias: cnt dead before tmp is written
  float* h1 = (float*)(ws + o_h1);
  float* h2 = (float*)(ws + o_h2);
  float* g = (float*)(ws + o_g);
  int* es = (int*)(ws + o_es);
  int* ed = (int*)(ws + o_ed);
  float* enorm = (float*)(ws + o_enorm);
  int* plist = (int*)(ws + o_plist);
  int* nodeoff = (int*)(ws + o_nodeoff);
  int* goff = (int*)(ws + o_goff);
  int* offr = (int*)(ws + o_offr);
  int* hist = (int*)(ws + o_hist);
  int* cur = (int*)(ws + o_cur);
  int* ndeg = (int*)(ws + o_ndeg);
  int* ncur = (int*)(ws + o_ncur);
  int* ghist = (int*)(ws + o_ghist);
  float* outp = (float*)d_out;

  hipMemsetAsync(ws + o_tmp, 0, (size_t)NN * NR * 4, stream);  // cnt
  hipMemsetAsync(ws + zs, 0, ze - zs, stream);                 // small counters

  // Preprocessing
  count_k<<<(NE + 255) / 256, 256, 0, stream>>>(edst, etype, cnt, hist, ndeg);
  gcount_k<<<(NN + 255) / 256, 256, 0, stream>>>(batch, ghist);
  scan_k<<<1, 256, 0, stream>>>(hist, offr, NR);
  scan_k<<<1, 256, 0, stream>>>(ndeg, nodeoff, NN);
  scan_k<<<1, 256, 0, stream>>>(ghist, goff, NG);
  scatter_k<<<(NE + 255) / 256, 256, 0, stream>>>(esrc, edst, etype, cnt, offr,
                                                  cur, es, ed, enorm);
  plist_k<<<(NE + 255) / 256, 256, 0, stream>>>(ed, nodeoff, ncur, plist);

  dim3 gRoot((NN + TE - 1) / TE, HD / TN);
  dim3 gEdge(NR * MAX_TILES, HD / TN);
  const int nReduceBlk = (NN * 64 + 255) / 256;

  // Layer 1: h1 = relu(x@root1 + b1 + scatter(tmp))
  gemm_root<FIN><<<gRoot, 256, 0, stream>>>(x, root1, b1, h1, NN);
  gemm_edge<FIN><<<gEdge, 256, 0, stream>>>(x, W1, es, enorm, offr, tmp);
  reduce_k<<<nReduceBlk, 256, 0, stream>>>(h1, tmp, nodeoff, plist);

  // Layer 2: h2 = relu(h1@root2 + b2 + scatter(tmp))
  gemm_root<HD><<<gRoot, 256, 0, stream>>>(h1, root2, b2, h2, NN);
  gemm_edge<HD><<<gEdge, 256, 0, stream>>>(h1, W2, es, enorm, offr, tmp);
  reduce_k<<<nReduceBlk, 256, 0, stream>>>(h2, tmp, nodeoff, plist);

  // Pooling + MLP head
  pool_k<<<(NG * 64 + 255) / 256, 256, 0, stream>>>(h2, wsw, wsb, goff, g);
  mlp_k<<<NG, 64, 0, stream>>>(g, m1, mb1, m2, mb2, m3, mb3, outp);
}

// Round 4
// 1092.816 us; speedup vs baseline: 2.2176x; 1.4468x over previous
//
#include <hip/hip_runtime.h>
#include <hip/hip_bf16.h>

// Problem constants (match reference)
#define NN 50000   // nodes
#define NE 150000  // edges
#define NR 65      // relations
#define NG 2000    // graphs
#define FIN 74     // input features
#define KP 96      // layer-1 K padded to multiple of TK (zero-filled)
#define HD 256     // hidden
#define MH 64      // mlp hidden

// GEMM tiling
#define TE 64      // rows per tile
#define TK 32      // k-chunk
#define MAX_TILES 40

// Async global->LDS, 16B per lane. LDS dest is wave-uniform base + lane*16.
__device__ __forceinline__ void gload_lds16(float* lds, const float* g) {
  __builtin_amdgcn_global_load_lds(
      (const __attribute__((address_space(1))) void*)g,
      (__attribute__((address_space(3))) void*)lds, 16, 0, 0);
}

// ---------------------------------------------------------------------------
// Padding copies (zero-filled K=96 versions for layer 1)
// ---------------------------------------------------------------------------
__global__ void padx_k(const float* __restrict__ x, float* __restrict__ xp) {
  int i = blockIdx.x * 256 + threadIdx.x;
  if (i < NN * KP) {
    int n = i / KP, k = i - n * KP;
    xp[i] = (k < FIN) ? x[(size_t)n * FIN + k] : 0.f;
  }
}

// w: [nmat][FIN][HD] -> wp: [nmat][KP][HD] (zero pad k in [FIN,KP))
__global__ void padw_k(const float* __restrict__ w, float* __restrict__ wp, int nmat) {
  int i = blockIdx.x * 256 + threadIdx.x;
  if (i < nmat * KP * (HD / 4)) {
    int c4 = i & (HD / 4 - 1);
    int rk = i / (HD / 4);
    int k = rk % KP, r = rk / KP;
    float4 v = make_float4(0.f, 0.f, 0.f, 0.f);
    if (k < FIN) v = *(const float4*)&w[((size_t)r * FIN + k) * HD + c4 * 4];
    *(float4*)&wp[((size_t)r * KP + k) * HD + c4 * 4] = v;
  }
}

// ---------------------------------------------------------------------------
// Edge preprocessing
// ---------------------------------------------------------------------------
__global__ void count_k(const int* __restrict__ dst, const int* __restrict__ et,
                        int* __restrict__ cnt, int* __restrict__ hist,
                        int* __restrict__ ndeg) {
  __shared__ int lh[NR];
  int t = threadIdx.x;
  if (t < NR) lh[t] = 0;
  __syncthreads();
  int e = blockIdx.x * 256 + t;
  if (e < NE) {
    int r = et[e], d = dst[e];
    atomicAdd(&cnt[(size_t)d * NR + r], 1);
    atomicAdd(&lh[r], 1);
    atomicAdd(&ndeg[d], 1);
  }
  __syncthreads();
  if (t < NR && lh[t]) atomicAdd(&hist[t], lh[t]);
}

__global__ void gcount_k(const int* __restrict__ batch, int* __restrict__ ghist) {
  int i = blockIdx.x * 256 + threadIdx.x;
  if (i < NN) atomicAdd(&ghist[batch[i]], 1);
}

// 1024-thread block exclusive scan: out[i]=sum(in[0..i-1]), out[n]=total.
__global__ __launch_bounds__(1024) void scan_k(const int* __restrict__ in,
                                               int* __restrict__ out, int n) {
  __shared__ int wsum[16];
  int t = threadIdx.x;
  int lane = t & 63, wid = t >> 6;
  int chunk = (n + 1023) / 1024;
  int lo = t * chunk;
  int hi = lo + chunk; if (hi > n) hi = n;
  int s = 0;
  for (int i = lo; i < hi; ++i) s += in[i];
  int v = s;
#pragma unroll
  for (int o = 1; o < 64; o <<= 1) {
    int u = __shfl_up(v, o, 64);
    if (lane >= o) v += u;
  }
  if (lane == 63) wsum[wid] = v;
  __syncthreads();
  if (wid == 0 && lane < 16) {
    int wv = wsum[lane];
#pragma unroll
    for (int o = 1; o < 16; o <<= 1) {
      int u = __shfl_up(wv, o, 64);
      if (lane >= o) wv += u;
    }
    wsum[lane] = wv;
  }
  __syncthreads();
  int base = (wid > 0 ? wsum[wid - 1] : 0) + (v - s);
  int acc = base;
  for (int i = lo; i < hi; ++i) { out[i] = acc; acc += in[i]; }
  if (hi == n && lo <= n) out[n] = acc;
}

// Counting-sort edges by relation; materialize norm = 1/cnt(dst,rel).
__global__ void scatter_k(const int* __restrict__ src, const int* __restrict__ dst,
                          const int* __restrict__ et, const int* __restrict__ cnt,
                          const int* __restrict__ offr, int* __restrict__ cur,
                          int* __restrict__ es, int* __restrict__ ed,
                          float* __restrict__ enorm) {
  int e = blockIdx.x * 256 + threadIdx.x;
  if (e < NE) {
    int r = et[e];
    int d = dst[e];
    int p = offr[r] + atomicAdd(&cur[r], 1);
    es[p] = src[e];
    ed[p] = d;
    int c = cnt[(size_t)d * NR + r];
    enorm[p] = 1.0f / (float)(c > 0 ? c : 1);
  }
}

// Sort edge positions p by dst into CSR (nodeoff, plist).
__global__ void plist_k(const int* __restrict__ ed, const int* __restrict__ nodeoff,
                        int* __restrict__ ncur, int* __restrict__ plist) {
  int p = blockIdx.x * 256 + threadIdx.x;
  if (p < NE) {
    int d = ed[p];
    int q = nodeoff[d] + atomicAdd(&ncur[d], 1);
    plist[q] = p;
  }
}

// ---------------------------------------------------------------------------
// Dense root GEMM: out[M][256] = X[M][K] @ W[K][256] + bias
// 256 thr, 64x256 tile, 8x8 register blocking, global_load_lds for W.
// ---------------------------------------------------------------------------
template<int K>
__global__ __launch_bounds__(256, 4) void gemm_root(const float* __restrict__ X,
                                                    const float* __restrict__ W,
                                                    const float* __restrict__ bias,
                                                    float* __restrict__ out, int M) {
  __shared__ float xs[TK][TE];
  __shared__ float ws[TK][HD];
  const int t = threadIdx.x;
  const int row0 = blockIdx.x * TE;
  const int lane = t & 63;
  const int wv = t >> 6;    // wave id (0..3)
  const int tcol = t & 31;  // 32 col groups
  const int trow = t >> 5;  // 8 row groups
  const int srow = t & 63;  // staging row
  const int skq = t >> 6;   // staging k-quad (8 floats each)

  float acc[8][8] = {};
  for (int k0 = 0; k0 < K; k0 += TK) {
    // W tile via async DMA: wave wv stages rows kk = wv*8..wv*8+7 (1KB each)
#pragma unroll
    for (int j = 0; j < 8; ++j) {
      int kk = wv * 8 + j;
      gload_lds16(&ws[kk][0], W + (size_t)(k0 + kk) * HD + lane * 4);
    }
    // X tile: thread loads 8 consecutive k of one row, writes transposed
    int gr = row0 + srow;
    float xv8[8];
    if (gr < M) {
      float4 a = *(const float4*)&X[(size_t)gr * K + k0 + skq * 8];
      float4 b = *(const float4*)&X[(size_t)gr * K + k0 + skq * 8 + 4];
      xv8[0] = a.x; xv8[1] = a.y; xv8[2] = a.z; xv8[3] = a.w;
      xv8[4] = b.x; xv8[5] = b.y; xv8[6] = b.z; xv8[7] = b.w;
    } else {
#pragma unroll
      for (int j = 0; j < 8; ++j) xv8[j] = 0.f;
    }
#pragma unroll
    for (int j = 0; j < 8; ++j) xs[skq * 8 + j][srow] = xv8[j];
    __syncthreads();
#pragma unroll 8
    for (int kk = 0; kk < TK; ++kk) {
      float4 wA = *(const float4*)&ws[kk][tcol * 4];
      float4 wB = *(const float4*)&ws[kk][128 + tcol * 4];
      float4 xA = *(const float4*)&xs[kk][trow * 8];
      float4 xB = *(const float4*)&xs[kk][trow * 8 + 4];
      float xv[8] = {xA.x, xA.y, xA.z, xA.w, xB.x, xB.y, xB.z, xB.w};
#pragma unroll
      for (int i = 0; i < 8; ++i) {
        acc[i][0] += xv[i] * wA.x;
        acc[i][1] += xv[i] * wA.y;
        acc[i][2] += xv[i] * wA.z;
        acc[i][3] += xv[i] * wA.w;
        acc[i][4] += xv[i] * wB.x;
        acc[i][5] += xv[i] * wB.y;
        acc[i][6] += xv[i] * wB.z;
        acc[i][7] += xv[i] * wB.w;
      }
    }
    __syncthreads();
  }
  float4 bA = *(const float4*)&bias[tcol * 4];
  float4 bB = *(const float4*)&bias[128 + tcol * 4];
#pragma unroll
  for (int i = 0; i < 8; ++i) {
    int gr = row0 + trow * 8 + i;
    if (gr < M) {
      float4 oA = make_float4(acc[i][0] + bA.x, acc[i][1] + bA.y,
                              acc[i][2] + bA.z, acc[i][3] + bA.w);
      float4 oB = make_float4(acc[i][4] + bB.x, acc[i][5] + bB.y,
                              acc[i][6] + bB.z, acc[i][7] + bB.w);
      *(float4*)&out[(size_t)gr * HD + tcol * 4] = oA;
      *(float4*)&out[(size_t)gr * HD + 128 + tcol * 4] = oB;
    }
  }
}

// ---------------------------------------------------------------------------
// Edge-batched segmented GEMM (rel-sorted): tmp[p] = (norm_p*X[es[p]]) @ W[rel]
// Same tile structure; rows gathered; coalesced stores, no atomics.
// ---------------------------------------------------------------------------
template<int K>
__global__ __launch_bounds__(256, 4) void gemm_edge(const float* __restrict__ X,
                                                    const float* __restrict__ Wall,
                                                    const int* __restrict__ es,
                                                    const float* __restrict__ enorm,
                                                    const int* __restrict__ offr,
                                                    float* __restrict__ tmp) {
  __shared__ float xs[TK][TE];
  __shared__ float ws[TK][HD];
  const int t = threadIdx.x;
  const int rel = blockIdx.x / MAX_TILES;
  const int tile = blockIdx.x % MAX_TILES;
  const int e_lo = offr[rel], e_hi = offr[rel + 1];
  if (e_lo + tile * TE >= e_hi) return;  // block-uniform early exit
  const float* W = Wall + (size_t)rel * K * HD;
  const int lane = t & 63;
  const int wv = t >> 6;
  const int tcol = t & 31;
  const int trow = t >> 5;
  const int srow = t & 63;
  const int skq = t >> 6;

  for (int base = e_lo + tile * TE; base < e_hi; base += MAX_TILES * TE) {
    const int nE = min(TE, e_hi - base);
    float acc[8][8] = {};
    for (int k0 = 0; k0 < K; k0 += TK) {
#pragma unroll
      for (int j = 0; j < 8; ++j) {
        int kk = wv * 8 + j;
        gload_lds16(&ws[kk][0], W + (size_t)(k0 + kk) * HD + lane * 4);
      }
      float xv8[8];
      if (srow < nE) {
        int s = es[base + srow];
        float nrm = enorm[base + srow];
        float4 a = *(const float4*)&X[(size_t)s * K + k0 + skq * 8];
        float4 b = *(const float4*)&X[(size_t)s * K + k0 + skq * 8 + 4];
        xv8[0] = a.x * nrm; xv8[1] = a.y * nrm; xv8[2] = a.z * nrm; xv8[3] = a.w * nrm;
        xv8[4] = b.x * nrm; xv8[5] = b.y * nrm; xv8[6] = b.z * nrm; xv8[7] = b.w * nrm;
      } else {
#pragma unroll
        for (int j = 0; j < 8; ++j) xv8[j] = 0.f;
      }
#pragma unroll
      for (int j = 0; j < 8; ++j) xs[skq * 8 + j][srow] = xv8[j];
      __syncthreads();
#pragma unroll 8
      for (int kk = 0; kk < TK; ++kk) {
        float4 wA = *(const float4*)&ws[kk][tcol * 4];
        float4 wB = *(const float4*)&ws[kk][128 + tcol * 4];
        float4 xA = *(const float4*)&xs[kk][trow * 8];
        float4 xB = *(const float4*)&xs[kk][trow * 8 + 4];
        float xv[8] = {xA.x, xA.y, xA.z, xA.w, xB.x, xB.y, xB.z, xB.w};
#pragma unroll
        for (int i = 0; i < 8; ++i) {
          acc[i][0] += xv[i] * wA.x;
          acc[i][1] += xv[i] * wA.y;
          acc[i][2] += xv[i] * wA.z;
          acc[i][3] += xv[i] * wA.w;
          acc[i][4] += xv[i] * wB.x;
          acc[i][5] += xv[i] * wB.y;
          acc[i][6] += xv[i] * wB.z;
          acc[i][7] += xv[i] * wB.w;
        }
      }
      __syncthreads();
    }
#pragma unroll
    for (int i = 0; i < 8; ++i) {
      int row = trow * 8 + i;
      if (row < nE) {
        float* o = &tmp[(size_t)(base + row) * HD];
        *(float4*)&o[tcol * 4] =
            make_float4(acc[i][0], acc[i][1], acc[i][2], acc[i][3]);
        *(float4*)&o[128 + tcol * 4] =
            make_float4(acc[i][4], acc[i][5], acc[i][6], acc[i][7]);
      }
    }
  }
}

// ---------------------------------------------------------------------------
// Per-node gather-reduce: h[n] = relu(h[n] + sum_{p in CSR[n]} tmp[p]).
// ---------------------------------------------------------------------------
__global__ __launch_bounds__(256) void reduce_k(float* __restrict__ h,
                                                const float* __restrict__ tmp,
                                                const int* __restrict__ nodeoff,
                                                const int* __restrict__ plist) {
  int wid = (blockIdx.x * 256 + threadIdx.x) >> 6;
  int lane = threadIdx.x & 63;
  if (wid >= NN) return;
  float* row = h + (size_t)wid * HD + lane * 4;
  float4 acc = *(float4*)row;
  int lo = nodeoff[wid], hi = nodeoff[wid + 1];
  for (int q = lo; q < hi; ++q) {
    int p = plist[q];
    float4 v = *(const float4*)&tmp[(size_t)p * HD + lane * 4];
    acc.x += v.x; acc.y += v.y; acc.z += v.z; acc.w += v.w;
  }
  acc.x = fmaxf(acc.x, 0.f);
  acc.y = fmaxf(acc.y, 0.f);
  acc.z = fmaxf(acc.z, 0.f);
  acc.w = fmaxf(acc.w, 0.f);
  *(float4*)row = acc;
}

// ---------------------------------------------------------------------------
// Pooling: batch sorted -> contiguous node range per graph; one wave/graph.
// ---------------------------------------------------------------------------
__global__ __launch_bounds__(256) void pool_k(const float* __restrict__ h,
                                              const float* __restrict__ wsw,
                                              const float* __restrict__ wsb,
                                              const int* __restrict__ goff,
                                              float* __restrict__ g) {
  int wid = (blockIdx.x * 256 + threadIdx.x) >> 6;
  int lane = threadIdx.x & 63;
  if (wid >= NG) return;
  float4 w4 = *(const float4*)&wsw[lane * 4];
  float wb = wsb[0];
  float4 acc = make_float4(0.f, 0.f, 0.f, 0.f);
  int lo = goff[wid], hi = goff[wid + 1];
  for (int n = lo; n < hi; ++n) {
    float4 v = *(const float4*)&h[(size_t)n * HD + lane * 4];
    float p = v.x * w4.x + v.y * w4.y + v.z * w4.z + v.w * w4.w;
#pragma unroll
    for (int o = 32; o > 0; o >>= 1) p += __shfl_xor(p, o, 64);
    float gate = 1.f / (1.f + expf(-(p + wb)));
    acc.x += gate * v.x;
    acc.y += gate * v.y;
    acc.z += gate * v.z;
    acc.w += gate * v.w;
  }
  *(float4*)&g[(size_t)wid * HD + lane * 4] = acc;
}

// Fused MLP head: one wave per graph. 256 -> 64 -> 64 -> 1
__global__ __launch_bounds__(64) void mlp_k(const float* __restrict__ g,
                                            const float* __restrict__ m1,
                                            const float* __restrict__ mb1,
                                            const float* __restrict__ m2,
                                            const float* __restrict__ mb2,
                                            const float* __restrict__ m3,
                                            const float* __restrict__ mb3,
                                            float* __restrict__ out) {
  __shared__ float sg[HD];
  __shared__ float s1[MH];
  int gr = blockIdx.x;
  int t = threadIdx.x;
  float4 v = *(const float4*)&g[(size_t)gr * HD + t * 4];
  *(float4*)&sg[t * 4] = v;
  __syncthreads();
  float a = mb1[t];
  for (int k = 0; k < HD; ++k) a += sg[k] * m1[k * MH + t];
  a = fmaxf(a, 0.f);
  s1[t] = a;
  __syncthreads();
  float b = mb2[t];
#pragma unroll
  for (int k = 0; k < MH; ++k) b += s1[k] * m2[k * MH + t];
  b = fmaxf(b, 0.f);
  float c = b * m3[t];
#pragma unroll
  for (int o = 32; o > 0; o >>= 1) c += __shfl_xor(c, o, 64);
  if (t == 0) out[gr] = c + mb3[0];
}

// ---------------------------------------------------------------------------
extern "C" void kernel_launch(void* const* d_in, const int* in_sizes, int n_in,
                              void* d_out, int out_size, void* d_ws, size_t ws_size,
                              hipStream_t stream) {
  const float* x = (const float*)d_in[0];
  const int* ei = (const int*)d_in[1];
  const int* etype = (const int*)d_in[2];
  const int* batch = (const int*)d_in[3];
  const float* W1 = (const float*)d_in[4];
  const float* root1 = (const float*)d_in[5];
  const float* b1 = (const float*)d_in[6];
  const float* W2 = (const float*)d_in[7];
  const float* root2 = (const float*)d_in[8];
  const float* b2 = (const float*)d_in[9];
  const float* wsw = (const float*)d_in[10];
  const float* wsb = (const float*)d_in[11];
  const float* m1 = (const float*)d_in[12];
  const float* mb1 = (const float*)d_in[13];
  const float* m2 = (const float*)d_in[14];
  const float* mb2 = (const float*)d_in[15];
  const float* m3 = (const float*)d_in[16];
  const float* mb3 = (const float*)d_in[17];
  const int* esrc = ei;
  const int* edst = ei + NE;

  // Workspace layout (256B aligned). Aliases:
  //   cnt  (NN*NR ints) over tmp head (dead before tmp written)
  //   Xp   (NN*KP)     over h2       (dead before h2 written)
  char* ws = (char*)d_ws;
  size_t off = 0;
  auto alloc = [&](size_t bytes) {
    size_t o = off;
    off = (off + bytes + 255) & ~(size_t)255;
    return o;
  };
  size_t o_tmp = alloc((size_t)NE * HD * 4);     // 153.6 MB
  size_t o_h1 = alloc((size_t)NN * HD * 4);      // 51.2 MB
  size_t o_h2x = alloc((size_t)NN * HD * 4);     // 51.2 MB (h2 | Xp union)
  size_t o_g = alloc((size_t)NG * HD * 4);
  size_t o_es = alloc((size_t)NE * 4);
  size_t o_ed = alloc((size_t)NE * 4);
  size_t o_enorm = alloc((size_t)NE * 4);
  size_t o_plist = alloc((size_t)NE * 4);
  size_t o_nodeoff = alloc((NN + 1) * 4);
  size_t o_goff = alloc((NG + 1) * 4);
  size_t o_offr = alloc((NR + 1) * 4);
  size_t o_wp1 = alloc((size_t)NR * KP * HD * 4);  // 6.4 MB
  size_t o_wr1 = alloc((size_t)KP * HD * 4);       // 98 KB
  size_t zs = off;  // zero region
  size_t o_hist = alloc(NR * 4);
  size_t o_cur = alloc(NR * 4);
  size_t o_ndeg = alloc((size_t)NN * 4);
  size_t o_ncur = alloc((size_t)NN * 4);
  size_t o_ghist = alloc((size_t)NG * 4);
  size_t ze = off;
  if (ws_size < off) return;  // insufficient scratch

  float* tmp = (float*)(ws + o_tmp);
  int* cnt = (int*)(ws + o_tmp);    // alias
  float* h1 = (float*)(ws + o_h1);
  float* h2 = (float*)(ws + o_h2x);
  float* xp = (float*)(ws + o_h2x); // alias
  float* g = (float*)(ws + o_g);
  int* es = (int*)(ws + o_es);
  int* ed = (int*)(ws + o_ed);
  float* enorm = (float*)(ws + o_enorm);
  int* plist = (int*)(ws + o_plist);
  int* nodeoff = (int*)(ws + o_nodeoff);
  int* goff = (int*)(ws + o_goff);
  int* offr = (int*)(ws + o_offr);
  float* wp1 = (float*)(ws + o_wp1);
  float* wr1 = (float*)(ws + o_wr1);
  int* hist = (int*)(ws + o_hist);
  int* cur = (int*)(ws + o_cur);
  int* ndeg = (int*)(ws + o_ndeg);
  int* ncur = (int*)(ws + o_ncur);
  int* ghist = (int*)(ws + o_ghist);
  float* outp = (float*)d_out;

  hipMemsetAsync(ws + o_tmp, 0, (size_t)NN * NR * 4, stream);  // cnt
  hipMemsetAsync(ws + zs, 0, ze - zs, stream);                 // counters

  // Padded copies for layer 1
  padx_k<<<(NN * KP + 255) / 256, 256, 0, stream>>>(x, xp);
  padw_k<<<(NR * KP * (HD / 4) + 255) / 256, 256, 0, stream>>>(W1, wp1, NR);
  padw_k<<<(KP * (HD / 4) + 255) / 256, 256, 0, stream>>>(root1, wr1, 1);

  // Preprocessing
  count_k<<<(NE + 255) / 256, 256, 0, stream>>>(edst, etype, cnt, hist, ndeg);
  gcount_k<<<(NN + 255) / 256, 256, 0, stream>>>(batch, ghist);
  scan_k<<<1, 1024, 0, stream>>>(hist, offr, NR);
  scan_k<<<1, 1024, 0, stream>>>(ndeg, nodeoff, NN);
  scan_k<<<1, 1024, 0, stream>>>(ghist, goff, NG);
  scatter_k<<<(NE + 255) / 256, 256, 0, stream>>>(esrc, edst, etype, cnt, offr,
                                                  cur, es, ed, enorm);
  plist_k<<<(NE + 255) / 256, 256, 0, stream>>>(ed, nodeoff, ncur, plist);

  const int gRoot = (NN + TE - 1) / TE;
  const int gEdge = NR * MAX_TILES;
  const int nReduceBlk = (NN * 64 + 255) / 256;

  // Layer 1: h1 = relu(xp@wr1 + b1 + gather(tmp))
  gemm_root<KP><<<gRoot, 256, 0, stream>>>(xp, wr1, b1, h1, NN);
  gemm_edge<KP><<<gEdge, 256, 0, stream>>>(xp, wp1, es, enorm, offr, tmp);
  reduce_k<<<nReduceBlk, 256, 0, stream>>>(h1, tmp, nodeoff, plist);

  // Layer 2: h2 = relu(h1@root2 + b2 + gather(tmp))   (xp dead from here)
  gemm_root<HD><<<gRoot, 256, 0, stream>>>(h1, root2, b2, h2, NN);
  gemm_edge<HD><<<gEdge, 256, 0, stream>>>(h1, W2, es, enorm, offr, tmp);
  reduce_k<<<nReduceBlk, 256, 0, stream>>>(h2, tmp, nodeoff, plist);

  // Pooling + MLP head
  pool_k<<<(NG * 64 + 255) / 256, 256, 0, stream>>>(h2, wsw, wsb, goff, g);
  mlp_k<<<NG, 64, 0, stream>>>(g, m1, mb1, m2, mb2, m3, mb3, outp);
}

// Round 5
// 872.188 us; speedup vs baseline: 2.7786x; 1.2530x over previous
//
#include <hip/hip_runtime.h>
#include <hip/hip_bf16.h>

// Problem constants
#define NN 50000
#define NE 150000
#define NR 65
#define NG 2000
#define FIN 74
#define KP 96      // layer-1 K padded (zero-filled)
#define HD 256
#define MH 64

#define TE2 128    // rows per GEMM tile
#define MAX_T2 20  // tile slots per relation (loop covers overflow)

typedef __attribute__((ext_vector_type(8))) short bf16x8;
typedef __attribute__((ext_vector_type(4))) float f32x4;

__device__ __forceinline__ unsigned short f2bf(float x) {
  unsigned u = __builtin_bit_cast(unsigned, x);
  u += 0x7FFF + ((u >> 16) & 1);  // RNE
  return (unsigned short)(u >> 16);
}
__device__ __forceinline__ float bf2f(unsigned short h) {
  unsigned u = (unsigned)h << 16;
  return __builtin_bit_cast(float, u);
}

__device__ __forceinline__ void gl16(const short* g, short* lds) {
  __builtin_amdgcn_global_load_lds(
      (const __attribute__((address_space(1))) void*)g,
      (__attribute__((address_space(3))) void*)lds, 16, 0, 0);
}

// ---------------------------------------------------------------------------
// Weight prep: fp32 W[nmat][Kin][256] -> bf16 hi/lo planes, transposed to
// [mat][half][plane][kstep][8 col-groups][1KB], with MFMA stacked-K perm and
// XOR bank-swizzle baked into the layout so GEMM stages it with linear DMA.
// slot (16B, 8 bf16) for (col, c): k = ks*32 + {c*4..c*4+3, 16+c*4..16+c*4+3}
// byte-in-8KB = grp*1024 + ((colin*64 + c*16) ^ ((colin&7)<<4))
// ---------------------------------------------------------------------------
__global__ void build_wt(const float* __restrict__ Wsrc, short* __restrict__ dst,
                         int Kin, int KC, int nmat) {
  int tid = blockIdx.x * 256 + threadIdx.x;
  int total = nmat * 2 * KC * 512;
  if (tid >= total) return;
  int c = tid & 3;
  int colin = (tid >> 2) & 15;
  int grp = (tid >> 6) & 7;
  int rem = tid >> 9;
  int ks = rem % KC;  rem /= KC;
  int half = rem & 1;
  int mat = rem >> 1;
  int col = half * 128 + grp * 16 + colin;
  bf16x8 hv, lv;
#pragma unroll
  for (int i = 0; i < 8; ++i) {
    int kk = (i < 4) ? (c * 4 + i) : (16 + c * 4 + (i - 4));
    int k = ks * 32 + kk;
    float v = (k < Kin) ? Wsrc[((size_t)mat * Kin + k) * HD + col] : 0.f;
    unsigned short h = f2bf(v);
    hv[i] = (short)h;
    lv[i] = (short)f2bf(v - bf2f(h));
  }
  int byteoff = grp * 1024 + ((colin * 64 + c * 16) ^ ((colin & 7) << 4));
  char* basehi = (char*)dst + ((size_t)((mat * 2 + half) * 2 + 0) * KC) * 8192;
  char* baselo = (char*)dst + ((size_t)((mat * 2 + half) * 2 + 1) * KC) * 8192;
  *(bf16x8*)(basehi + (size_t)ks * 8192 + byteoff) = hv;
  *(bf16x8*)(baselo + (size_t)ks * 8192 + byteoff) = lv;
}

// x [NN][74] -> xp [NN][96] zero-padded
__global__ void padx_k(const float* __restrict__ x, float* __restrict__ xp) {
  int i = blockIdx.x * 256 + threadIdx.x;
  if (i < NN * KP) {
    int n = i / KP, k = i - n * KP;
    xp[i] = (k < FIN) ? x[(size_t)n * FIN + k] : 0.f;
  }
}

// ---------------------------------------------------------------------------
// Edge preprocessing (unchanged from round 4)
// ---------------------------------------------------------------------------
__global__ void count_k(const int* __restrict__ dst, const int* __restrict__ et,
                        int* __restrict__ cnt, int* __restrict__ hist,
                        int* __restrict__ ndeg) {
  __shared__ int lh[NR];
  int t = threadIdx.x;
  if (t < NR) lh[t] = 0;
  __syncthreads();
  int e = blockIdx.x * 256 + t;
  if (e < NE) {
    int r = et[e], d = dst[e];
    atomicAdd(&cnt[(size_t)d * NR + r], 1);
    atomicAdd(&lh[r], 1);
    atomicAdd(&ndeg[d], 1);
  }
  __syncthreads();
  if (t < NR && lh[t]) atomicAdd(&hist[t], lh[t]);
}

__global__ void gcount_k(const int* __restrict__ batch, int* __restrict__ ghist) {
  int i = blockIdx.x * 256 + threadIdx.x;
  if (i < NN) atomicAdd(&ghist[batch[i]], 1);
}

__global__ __launch_bounds__(1024) void scan_k(const int* __restrict__ in,
                                               int* __restrict__ out, int n) {
  __shared__ int wsum[16];
  int t = threadIdx.x;
  int lane = t & 63, wid = t >> 6;
  int chunk = (n + 1023) / 1024;
  int lo = t * chunk;
  int hi = lo + chunk; if (hi > n) hi = n;
  int s = 0;
  for (int i = lo; i < hi; ++i) s += in[i];
  int v = s;
#pragma unroll
  for (int o = 1; o < 64; o <<= 1) {
    int u = __shfl_up(v, o, 64);
    if (lane >= o) v += u;
  }
  if (lane == 63) wsum[wid] = v;
  __syncthreads();
  if (wid == 0 && lane < 16) {
    int wv = wsum[lane];
#pragma unroll
    for (int o = 1; o < 16; o <<= 1) {
      int u = __shfl_up(wv, o, 64);
      if (lane >= o) wv += u;
    }
    wsum[lane] = wv;
  }
  __syncthreads();
  int base = (wid > 0 ? wsum[wid - 1] : 0) + (v - s);
  int acc = base;
  for (int i = lo; i < hi; ++i) { out[i] = acc; acc += in[i]; }
  if (hi == n && lo <= n) out[n] = acc;
}

__global__ void scatter_k(const int* __restrict__ src, const int* __restrict__ dst,
                          const int* __restrict__ et, const int* __restrict__ cnt,
                          const int* __restrict__ offr, int* __restrict__ cur,
                          int* __restrict__ es, int* __restrict__ ed,
                          float* __restrict__ enorm) {
  int e = blockIdx.x * 256 + threadIdx.x;
  if (e < NE) {
    int r = et[e];
    int d = dst[e];
    int p = offr[r] + atomicAdd(&cur[r], 1);
    es[p] = src[e];
    ed[p] = d;
    int c = cnt[(size_t)d * NR + r];
    enorm[p] = 1.0f / (float)(c > 0 ? c : 1);
  }
}

__global__ void plist_k(const int* __restrict__ ed, const int* __restrict__ nodeoff,
                        int* __restrict__ ncur, int* __restrict__ plist) {
  int p = blockIdx.x * 256 + threadIdx.x;
  if (p < NE) {
    int d = ed[p];
    int q = nodeoff[d] + atomicAdd(&ncur[d], 1);
    plist[q] = p;
  }
}

// ---------------------------------------------------------------------------
// MFMA GEMM core helpers (shared shape: 128 rows x 128 cols, 4 waves 2x2,
// each wave 4x4 frags of 16x16x32, bf16x2 split => 48 MFMA / wave / k-step)
// ---------------------------------------------------------------------------
#define MFMA_BF16 __builtin_amdgcn_mfma_f32_16x16x32_bf16

// ---------------------------------------------------------------------------
// Edge-batched segmented GEMM: tmp[p][0..127] = (norm_p * X[es[p]]) @ Wt[rel]
// for one 128-col half. Pre-swizzled Wt staged via linear global_load_lds.
// ---------------------------------------------------------------------------
template<int K>
__global__ __launch_bounds__(256) void gemm_edge(const float* __restrict__ X,
                                                 const short* __restrict__ Wt,
                                                 const int* __restrict__ es,
                                                 const float* __restrict__ enorm,
                                                 const int* __restrict__ offr,
                                                 float* __restrict__ tmp,
                                                 int half) {
  constexpr int KC = K / 32;
  __shared__ __align__(16) short Ah[4096], Al[4096], Bh[4096], Bl[4096];
  const int t = threadIdx.x;
  const int rel = blockIdx.x / MAX_T2;
  const int tile = blockIdx.x % MAX_T2;
  const int e_lo = offr[rel], e_hi = offr[rel + 1];
  if (e_lo + tile * TE2 >= e_hi) return;
  const short* WtM = Wt + (size_t)(rel * 2 + half) * (2 * KC * 4096);
  const int lane = t & 63, wv = t >> 6;
  const int r = t & 127, cp = t >> 7;           // staging: row, c-pair
  const int rowb = (wv & 1) * 64, colb = (wv >> 1) * 64;
  const int fo = (((lane & 15) * 64 + (lane >> 4) * 16) ^ ((lane & 7) << 4)) >> 1;

  for (int base = e_lo + tile * TE2; base < e_hi; base += MAX_T2 * TE2) {
    const int nE = min(TE2, e_hi - base);
    const float* xrow = X + (size_t)es[base + ((r < nE) ? r : 0)] * K;
    const float nrm = (r < nE) ? enorm[base + r] : 0.f;
    f32x4 acc[4][4];
#pragma unroll
    for (int f = 0; f < 4; ++f)
#pragma unroll
      for (int n = 0; n < 4; ++n) acc[f][n] = {0.f, 0.f, 0.f, 0.f};

    for (int ks = 0; ks < KC; ++ks) {
      // B: 8KB/plane via DMA, 2 chunks x 2 planes per wave
#pragma unroll
      for (int j = 0; j < 2; ++j) {
        int ch = wv * 2 + j;
        gl16(WtM + (size_t)ks * 4096 + ch * 512 + lane * 8, &Bh[ch * 512]);
        gl16(WtM + (size_t)(KC + ks) * 4096 + ch * 512 + lane * 8, &Bl[ch * 512]);
      }
      // A: gather + norm + split + swizzled ds_write_b128
#pragma unroll
      for (int j = 0; j < 2; ++j) {
        int c = cp * 2 + j;
        float4 a = *(const float4*)&xrow[ks * 32 + c * 4];
        float4 b = *(const float4*)&xrow[ks * 32 + 16 + c * 4];
        float v[8] = {a.x * nrm, a.y * nrm, a.z * nrm, a.w * nrm,
                      b.x * nrm, b.y * nrm, b.z * nrm, b.w * nrm};
        bf16x8 hv, lv;
#pragma unroll
        for (int i = 0; i < 8; ++i) {
          unsigned short h = f2bf(v[i]);
          hv[i] = (short)h;
          lv[i] = (short)f2bf(v[i] - bf2f(h));
        }
        int ab = (r * 64 + c * 16) ^ ((r & 7) << 4);
        *(bf16x8*)((char*)Ah + ab) = hv;
        *(bf16x8*)((char*)Al + ab) = lv;
      }
      __syncthreads();
      bf16x8 afh[4], afl[4], bfh[4], bfl[4];
#pragma unroll
      for (int f = 0; f < 4; ++f) {
        int o = (rowb + f * 16) * 32 + fo;
        afh[f] = *(const bf16x8*)&Ah[o];
        afl[f] = *(const bf16x8*)&Al[o];
      }
#pragma unroll
      for (int n = 0; n < 4; ++n) {
        int o = (colb + n * 16) * 32 + fo;
        bfh[n] = *(const bf16x8*)&Bh[o];
        bfl[n] = *(const bf16x8*)&Bl[o];
      }
#pragma unroll
      for (int f = 0; f < 4; ++f)
#pragma unroll
        for (int n = 0; n < 4; ++n) {
          acc[f][n] = MFMA_BF16(afh[f], bfh[n], acc[f][n], 0, 0, 0);
          acc[f][n] = MFMA_BF16(afh[f], bfl[n], acc[f][n], 0, 0, 0);
          acc[f][n] = MFMA_BF16(afl[f], bfh[n], acc[f][n], 0, 0, 0);
        }
      __syncthreads();
    }
    // D layout: row=(lane>>4)*4+reg, col=lane&15 (verified m89/m91)
#pragma unroll
    for (int f = 0; f < 4; ++f) {
      int rb = rowb + f * 16 + (lane >> 4) * 4;
#pragma unroll
      for (int rr = 0; rr < 4; ++rr) {
        int row = rb + rr;
        if (row < nE) {
          float* o = &tmp[(size_t)(base + row) * 128 + colb + (lane & 15)];
#pragma unroll
          for (int n = 0; n < 4; ++n) o[n * 16] = acc[f][n][rr];
        }
      }
    }
  }
}

// ---------------------------------------------------------------------------
// Dense root GEMM: out[M][256] = X[M][K] @ W + bias, one 128-col half per
// blockIdx.y. Same MFMA structure.
// ---------------------------------------------------------------------------
template<int K>
__global__ __launch_bounds__(256) void gemm_root(const float* __restrict__ X,
                                                 const short* __restrict__ Wtr,
                                                 const float* __restrict__ bias,
                                                 float* __restrict__ out, int M) {
  constexpr int KC = K / 32;
  __shared__ __align__(16) short Ah[4096], Al[4096], Bh[4096], Bl[4096];
  const int t = threadIdx.x;
  const int row0 = blockIdx.x * TE2;
  const int half = blockIdx.y;
  const short* WtM = Wtr + (size_t)half * (2 * KC * 4096);
  const int lane = t & 63, wv = t >> 6;
  const int r = t & 127, cp = t >> 7;
  const int rowb = (wv & 1) * 64, colb = (wv >> 1) * 64;
  const int fo = (((lane & 15) * 64 + (lane >> 4) * 16) ^ ((lane & 7) << 4)) >> 1;

  const int gr = row0 + r;
  const float* xrow = X + (size_t)(gr < M ? gr : 0) * K;
  const float nrm = (gr < M) ? 1.f : 0.f;
  f32x4 acc[4][4];
#pragma unroll
  for (int f = 0; f < 4; ++f)
#pragma unroll
    for (int n = 0; n < 4; ++n) acc[f][n] = {0.f, 0.f, 0.f, 0.f};

  for (int ks = 0; ks < KC; ++ks) {
#pragma unroll
    for (int j = 0; j < 2; ++j) {
      int ch = wv * 2 + j;
      gl16(WtM + (size_t)ks * 4096 + ch * 512 + lane * 8, &Bh[ch * 512]);
      gl16(WtM + (size_t)(KC + ks) * 4096 + ch * 512 + lane * 8, &Bl[ch * 512]);
    }
#pragma unroll
    for (int j = 0; j < 2; ++j) {
      int c = cp * 2 + j;
      float4 a = *(const float4*)&xrow[ks * 32 + c * 4];
      float4 b = *(const float4*)&xrow[ks * 32 + 16 + c * 4];
      float v[8] = {a.x * nrm, a.y * nrm, a.z * nrm, a.w * nrm,
                    b.x * nrm, b.y * nrm, b.z * nrm, b.w * nrm};
      bf16x8 hv, lv;
#pragma unroll
      for (int i = 0; i < 8; ++i) {
        unsigned short h = f2bf(v[i]);
        hv[i] = (short)h;
        lv[i] = (short)f2bf(v[i] - bf2f(h));
      }
      int ab = (r * 64 + c * 16) ^ ((r & 7) << 4);
      *(bf16x8*)((char*)Ah + ab) = hv;
      *(bf16x8*)((char*)Al + ab) = lv;
    }
    __syncthreads();
    bf16x8 afh[4], afl[4], bfh[4], bfl[4];
#pragma unroll
    for (int f = 0; f < 4; ++f) {
      int o = (rowb + f * 16) * 32 + fo;
      afh[f] = *(const bf16x8*)&Ah[o];
      afl[f] = *(const bf16x8*)&Al[o];
    }
#pragma unroll
    for (int n = 0; n < 4; ++n) {
      int o = (colb + n * 16) * 32 + fo;
      bfh[n] = *(const bf16x8*)&Bh[o];
      bfl[n] = *(const bf16x8*)&Bl[o];
    }
#pragma unroll
    for (int f = 0; f < 4; ++f)
#pragma unroll
      for (int n = 0; n < 4; ++n) {
        acc[f][n] = MFMA_BF16(afh[f], bfh[n], acc[f][n], 0, 0, 0);
        acc[f][n] = MFMA_BF16(afh[f], bfl[n], acc[f][n], 0, 0, 0);
        acc[f][n] = MFMA_BF16(afl[f], bfh[n], acc[f][n], 0, 0, 0);
      }
    __syncthreads();
  }
#pragma unroll
  for (int f = 0; f < 4; ++f) {
    int rb = rowb + f * 16 + (lane >> 4) * 4;
#pragma unroll
    for (int rr = 0; rr < 4; ++rr) {
      int row = rb + rr;
      if (row0 + row < M) {
#pragma unroll
        for (int n = 0; n < 4; ++n) {
          int cg = half * 128 + colb + n * 16 + (lane & 15);
          out[(size_t)(row0 + row) * HD + cg] = acc[f][n][rr] + bias[cg];
        }
      }
    }
  }
}

// ---------------------------------------------------------------------------
// Per-node gather-reduce over one 128-col half: h[n][col0..] = relu(h + sum tmp)
// ---------------------------------------------------------------------------
__global__ __launch_bounds__(256) void reduce_k(float* __restrict__ h,
                                                const float* __restrict__ tmp,
                                                const int* __restrict__ nodeoff,
                                                const int* __restrict__ plist,
                                                int col0) {
  int wid = (blockIdx.x * 256 + threadIdx.x) >> 6;
  int lane = threadIdx.x & 63;
  if (wid >= NN) return;
  float* row = h + (size_t)wid * HD + col0 + lane * 2;
  float2 acc = *(float2*)row;
  int lo = nodeoff[wid], hi = nodeoff[wid + 1];
  for (int q = lo; q < hi; ++q) {
    int p = plist[q];
    float2 v = *(const float2*)&tmp[(size_t)p * 128 + lane * 2];
    acc.x += v.x; acc.y += v.y;
  }
  acc.x = fmaxf(acc.x, 0.f);
  acc.y = fmaxf(acc.y, 0.f);
  *(float2*)row = acc;
}

// ---------------------------------------------------------------------------
// Pooling (batch sorted -> contiguous ranges) and fused MLP head (unchanged)
// ---------------------------------------------------------------------------
__global__ __launch_bounds__(256) void pool_k(const float* __restrict__ h,
                                              const float* __restrict__ wsw,
                                              const float* __restrict__ wsb,
                                              const int* __restrict__ goff,
                                              float* __restrict__ g) {
  int wid = (blockIdx.x * 256 + threadIdx.x) >> 6;
  int lane = threadIdx.x & 63;
  if (wid >= NG) return;
  float4 w4 = *(const float4*)&wsw[lane * 4];
  float wb = wsb[0];
  float4 acc = make_float4(0.f, 0.f, 0.f, 0.f);
  int lo = goff[wid], hi = goff[wid + 1];
  for (int n = lo; n < hi; ++n) {
    float4 v = *(const float4*)&h[(size_t)n * HD + lane * 4];
    float p = v.x * w4.x + v.y * w4.y + v.z * w4.z + v.w * w4.w;
#pragma unroll
    for (int o = 32; o > 0; o >>= 1) p += __shfl_xor(p, o, 64);
    float gate = 1.f / (1.f + expf(-(p + wb)));
    acc.x += gate * v.x;
    acc.y += gate * v.y;
    acc.z += gate * v.z;
    acc.w += gate * v.w;
  }
  *(float4*)&g[(size_t)wid * HD + lane * 4] = acc;
}

__global__ __launch_bounds__(64) void mlp_k(const float* __restrict__ g,
                                            const float* __restrict__ m1,
                                            const float* __restrict__ mb1,
                                            const float* __restrict__ m2,
                                            const float* __restrict__ mb2,
                                            const float* __restrict__ m3,
                                            const float* __restrict__ mb3,
                                            float* __restrict__ out) {
  __shared__ float sg[HD];
  __shared__ float s1[MH];
  int gr = blockIdx.x;
  int t = threadIdx.x;
  float4 v = *(const float4*)&g[(size_t)gr * HD + t * 4];
  *(float4*)&sg[t * 4] = v;
  __syncthreads();
  float a = mb1[t];
  for (int k = 0; k < HD; ++k) a += sg[k] * m1[k * MH + t];
  a = fmaxf(a, 0.f);
  s1[t] = a;
  __syncthreads();
  float b = mb2[t];
#pragma unroll
  for (int k = 0; k < MH; ++k) b += s1[k] * m2[k * MH + t];
  b = fmaxf(b, 0.f);
  float c = b * m3[t];
#pragma unroll
  for (int o = 32; o > 0; o >>= 1) c += __shfl_xor(c, o, 64);
  if (t == 0) out[gr] = c + mb3[0];
}

// ---------------------------------------------------------------------------
extern "C" void kernel_launch(void* const* d_in, const int* in_sizes, int n_in,
                              void* d_out, int out_size, void* d_ws, size_t ws_size,
                              hipStream_t stream) {
  const float* x = (const float*)d_in[0];
  const int* ei = (const int*)d_in[1];
  const int* etype = (const int*)d_in[2];
  const int* batch = (const int*)d_in[3];
  const float* W1 = (const float*)d_in[4];
  const float* root1 = (const float*)d_in[5];
  const float* b1 = (const float*)d_in[6];
  const float* W2 = (const float*)d_in[7];
  const float* root2 = (const float*)d_in[8];
  const float* b2 = (const float*)d_in[9];
  const float* wsw = (const float*)d_in[10];
  const float* wsb = (const float*)d_in[11];
  const float* m1 = (const float*)d_in[12];
  const float* mb1 = (const float*)d_in[13];
  const float* m2 = (const float*)d_in[14];
  const float* mb2 = (const float*)d_in[15];
  const float* m3 = (const float*)d_in[16];
  const float* mb3 = (const float*)d_in[17];
  const int* esrc = ei;
  const int* edst = ei + NE;

  constexpr int KC1 = KP / 32;  // 3
  constexpr int KC2 = HD / 32;  // 8

  // Workspace layout (256B aligned). Aliases:
  //   cnt (NN*NR ints)        over tmp head   (dead before tmp written)
  //   xp / wt1 / wtr1         inside h2       (dead before L2 root writes h2)
  char* ws = (char*)d_ws;
  size_t off = 0;
  auto alloc = [&](size_t bytes) {
    size_t o = off;
    off = (off + bytes + 255) & ~(size_t)255;
    return o;
  };
  size_t o_tmp = alloc((size_t)NE * 128 * 4);      // 76.8 MB (col-half tmp)
  size_t o_h1 = alloc((size_t)NN * HD * 4);        // 51.2 MB
  size_t o_h2x = alloc((size_t)NN * HD * 4);       // 51.2 MB (h2 | xp+wt1+wtr1)
  size_t o_g = alloc((size_t)NG * HD * 4);
  size_t o_es = alloc((size_t)NE * 4);
  size_t o_ed = alloc((size_t)NE * 4);
  size_t o_enorm = alloc((size_t)NE * 4);
  size_t o_plist = alloc((size_t)NE * 4);
  size_t o_nodeoff = alloc((NN + 1) * 4);
  size_t o_goff = alloc((NG + 1) * 4);
  size_t o_offr = alloc((NR + 1) * 4);
  size_t o_wt2 = alloc((size_t)NR * 4 * KC2 * 4096 * 2);  // 17.04 MB
  size_t o_wtr2 = alloc((size_t)4 * KC2 * 4096 * 2);      // 262 KB
  size_t zs = off;  // zero region
  size_t o_hist = alloc(NR * 4);
  size_t o_cur = alloc(NR * 4);
  size_t o_ndeg = alloc((size_t)NN * 4);
  size_t o_ncur = alloc((size_t)NN * 4);
  size_t o_ghist = alloc((size_t)NG * 4);
  size_t ze = off;
  if (ws_size < off) return;

  float* tmp = (float*)(ws + o_tmp);
  int* cnt = (int*)(ws + o_tmp);                   // alias
  float* h1 = (float*)(ws + o_h1);
  float* h2 = (float*)(ws + o_h2x);
  float* xp = (float*)(ws + o_h2x);                // alias (19.2 MB)
  short* wt1 = (short*)(ws + o_h2x + 19200000);    // alias (6.39 MB)
  short* wtr1 = (short*)(ws + o_h2x + 19200000 + 6389760);  // alias (98 KB)
  float* g = (float*)(ws + o_g);
  int* es = (int*)(ws + o_es);
  int* ed = (int*)(ws + o_ed);
  float* enorm = (float*)(ws + o_enorm);
  int* plist = (int*)(ws + o_plist);
  int* nodeoff = (int*)(ws + o_nodeoff);
  int* goff = (int*)(ws + o_goff);
  int* offr = (int*)(ws + o_offr);
  short* wt2 = (short*)(ws + o_wt2);
  short* wtr2 = (short*)(ws + o_wtr2);
  int* hist = (int*)(ws + o_hist);
  int* cur = (int*)(ws + o_cur);
  int* ndeg = (int*)(ws + o_ndeg);
  int* ncur = (int*)(ws + o_ncur);
  int* ghist = (int*)(ws + o_ghist);
  float* outp = (float*)d_out;

  hipMemsetAsync(ws + o_tmp, 0, (size_t)NN * NR * 4, stream);  // cnt
  hipMemsetAsync(ws + zs, 0, ze - zs, stream);

  // Weight prep (transposed + split + swizzled) and padded x
  padx_k<<<(NN * KP + 255) / 256, 256, 0, stream>>>(x, xp);
  build_wt<<<(NR * 2 * KC1 * 512 + 255) / 256, 256, 0, stream>>>(W1, wt1, FIN, KC1, NR);
  build_wt<<<(2 * KC1 * 512 + 255) / 256, 256, 0, stream>>>(root1, wtr1, FIN, KC1, 1);
  build_wt<<<(NR * 2 * KC2 * 512 + 255) / 256, 256, 0, stream>>>(W2, wt2, HD, KC2, NR);
  build_wt<<<(2 * KC2 * 512 + 255) / 256, 256, 0, stream>>>(root2, wtr2, HD, KC2, 1);

  // Edge preprocessing
  count_k<<<(NE + 255) / 256, 256, 0, stream>>>(edst, etype, cnt, hist, ndeg);
  gcount_k<<<(NN + 255) / 256, 256, 0, stream>>>(batch, ghist);
  scan_k<<<1, 1024, 0, stream>>>(hist, offr, NR);
  scan_k<<<1, 1024, 0, stream>>>(ndeg, nodeoff, NN);
  scan_k<<<1, 1024, 0, stream>>>(ghist, goff, NG);
  scatter_k<<<(NE + 255) / 256, 256, 0, stream>>>(esrc, edst, etype, cnt, offr,
                                                  cur, es, ed, enorm);
  plist_k<<<(NE + 255) / 256, 256, 0, stream>>>(ed, nodeoff, ncur, plist);

  const dim3 gRoot((NN + TE2 - 1) / TE2, 2);
  const int gEdge = NR * MAX_T2;
  const int nRed = (NN * 64 + 255) / 256;

  // Layer 1
  gemm_root<KP><<<gRoot, 256, 0, stream>>>(xp, wtr1, b1, h1, NN);
  gemm_edge<KP><<<gEdge, 256, 0, stream>>>(xp, wt1, es, enorm, offr, tmp, 0);
  reduce_k<<<nRed, 256, 0, stream>>>(h1, tmp, nodeoff, plist, 0);
  gemm_edge<KP><<<gEdge, 256, 0, stream>>>(xp, wt1, es, enorm, offr, tmp, 1);
  reduce_k<<<nRed, 256, 0, stream>>>(h1, tmp, nodeoff, plist, 128);

  // Layer 2 (xp/wt1/wtr1 dead; h2 written by root)
  gemm_root<HD><<<gRoot, 256, 0, stream>>>(h1, wtr2, b2, h2, NN);
  gemm_edge<HD><<<gEdge, 256, 0, stream>>>(h1, wt2, es, enorm, offr, tmp, 0);
  reduce_k<<<nRed, 256, 0, stream>>>(h2, tmp, nodeoff, plist, 0);
  gemm_edge<HD><<<gEdge, 256, 0, stream>>>(h1, wt2, es, enorm, offr, tmp, 1);
  reduce_k<<<nRed, 256, 0, stream>>>(h2, tmp, nodeoff, plist, 128);

  // Pooling + MLP head
  pool_k<<<(NG * 64 + 255) / 256, 256, 0, stream>>>(h2, wsw, wsb, goff, g);
  mlp_k<<<NG, 64, 0, stream>>>(g, m1, mb1, m2, mb2, m3, mb3, outp);
}

// Round 6
// 647.748 us; speedup vs baseline: 3.7414x; 1.3465x over previous
//
#include <hip/hip_runtime.h>
#include <hip/hip_bf16.h>

// Problem constants
#define NN 50000
#define NE 150000
#define NR 65
#define NG 2000
#define FIN 74
#define KP 96      // layer-1 K padded (zero-filled)
#define HD 256
#define MH 64

#define TE2 128    // rows per GEMM tile
#define MAX_T2 20  // tile slots per relation (loop covers overflow)

#define EPB 1024                    // edges per sort block
#define NB ((NE + EPB - 1) / EPB)   // 147
#define NTOT (NR * NB)              // 9555

typedef __attribute__((ext_vector_type(8))) short bf16x8;
typedef __attribute__((ext_vector_type(4))) float f32x4;

__device__ __forceinline__ unsigned short f2bf(float x) {
  unsigned u = __builtin_bit_cast(unsigned, x);
  u += 0x7FFF + ((u >> 16) & 1);  // RNE
  return (unsigned short)(u >> 16);
}
__device__ __forceinline__ float bf2f(unsigned short h) {
  unsigned u = (unsigned)h << 16;
  return __builtin_bit_cast(float, u);
}

__device__ __forceinline__ void gl16(const short* g, short* lds) {
  __builtin_amdgcn_global_load_lds(
      (const __attribute__((address_space(1))) void*)g,
      (__attribute__((address_space(3))) void*)lds, 16, 0, 0);
}

// ---------------------------------------------------------------------------
// Weight prep: fp32 W[nmat][Kin][256] -> bf16 hi/lo planes, transposed to
// [mat][half][plane][kstep][8 col-groups][1KB], MFMA stacked-K perm + XOR
// bank-swizzle baked in so GEMM stages it with linear global_load_lds.
// ---------------------------------------------------------------------------
__global__ void build_wt(const float* __restrict__ Wsrc, short* __restrict__ dst,
                         int Kin, int KC, int nmat) {
  int tid = blockIdx.x * 256 + threadIdx.x;
  int total = nmat * 2 * KC * 512;
  if (tid >= total) return;
  int c = tid & 3;
  int colin = (tid >> 2) & 15;
  int grp = (tid >> 6) & 7;
  int rem = tid >> 9;
  int ks = rem % KC;  rem /= KC;
  int half = rem & 1;
  int mat = rem >> 1;
  int col = half * 128 + grp * 16 + colin;
  bf16x8 hv, lv;
#pragma unroll
  for (int i = 0; i < 8; ++i) {
    int kk = (i < 4) ? (c * 4 + i) : (16 + c * 4 + (i - 4));
    int k = ks * 32 + kk;
    float v = (k < Kin) ? Wsrc[((size_t)mat * Kin + k) * HD + col] : 0.f;
    unsigned short h = f2bf(v);
    hv[i] = (short)h;
    lv[i] = (short)f2bf(v - bf2f(h));
  }
  int byteoff = grp * 1024 + ((colin * 64 + c * 16) ^ ((colin & 7) << 4));
  char* basehi = (char*)dst + ((size_t)((mat * 2 + half) * 2 + 0) * KC) * 8192;
  char* baselo = (char*)dst + ((size_t)((mat * 2 + half) * 2 + 1) * KC) * 8192;
  *(bf16x8*)(basehi + (size_t)ks * 8192 + byteoff) = hv;
  *(bf16x8*)(baselo + (size_t)ks * 8192 + byteoff) = lv;
}

// x [NN][74] -> xp [NN][96] zero-padded
__global__ void padx_k(const float* __restrict__ x, float* __restrict__ xp) {
  int i = blockIdx.x * 256 + threadIdx.x;
  if (i < NN * KP) {
    int n = i / KP, k = i - n * KP;
    xp[i] = (k < FIN) ? x[(size_t)n * FIN + k] : 0.f;
  }
}

// ---------------------------------------------------------------------------
// Edge preprocessing — contention-free counting sort by relation.
// ---------------------------------------------------------------------------
// Per-(dst,rel) and per-dst degree counts (atomics over 3.25M / 50K addrs —
// negligible contention; the old 65-counter global atomics are GONE).
__global__ void count_k(const int* __restrict__ dst, const int* __restrict__ et,
                        int* __restrict__ cnt, int* __restrict__ ndeg) {
  int e = blockIdx.x * 256 + threadIdx.x;
  if (e < NE) {
    atomicAdd(&cnt[(size_t)dst[e] * NR + et[e]], 1);
    atomicAdd(&ndeg[dst[e]], 1);
  }
}

__global__ void gcount_k(const int* __restrict__ batch, int* __restrict__ ghist) {
  int i = blockIdx.x * 256 + threadIdx.x;
  if (i < NN) atomicAdd(&ghist[batch[i]], 1);
}

// Per-block relation histogram -> bh[r*NB + b] (LDS-aggregated, no global atomics)
__global__ __launch_bounds__(EPB) void histblk_k(const int* __restrict__ et,
                                                 int* __restrict__ bh) {
  __shared__ int lh[NR];
  int t = threadIdx.x, b = blockIdx.x;
  if (t < NR) lh[t] = 0;
  __syncthreads();
  int e = b * EPB + t;
  if (e < NE) atomicAdd(&lh[et[e]], 1);
  __syncthreads();
  if (t < NR) bh[t * NB + b] = lh[t];
}

// 1024-thread block exclusive scan: out[i]=sum(in[0..i-1]), out[n]=total.
__global__ __launch_bounds__(1024) void scan_k(const int* __restrict__ in,
                                               int* __restrict__ out, int n) {
  __shared__ int wsum[16];
  int t = threadIdx.x;
  int lane = t & 63, wid = t >> 6;
  int chunk = (n + 1023) / 1024;
  int lo = t * chunk;
  int hi = lo + chunk; if (hi > n) hi = n;
  int s = 0;
  for (int i = lo; i < hi; ++i) s += in[i];
  int v = s;
#pragma unroll
  for (int o = 1; o < 64; o <<= 1) {
    int u = __shfl_up(v, o, 64);
    if (lane >= o) v += u;
  }
  if (lane == 63) wsum[wid] = v;
  __syncthreads();
  if (wid == 0 && lane < 16) {
    int wv = wsum[lane];
#pragma unroll
    for (int o = 1; o < 16; o <<= 1) {
      int u = __shfl_up(wv, o, 64);
      if (lane >= o) wv += u;
    }
    wsum[lane] = wv;
  }
  __syncthreads();
  int base = (wid > 0 ? wsum[wid - 1] : 0) + (v - s);
  int acc = base;
  for (int i = lo; i < hi; ++i) { out[i] = acc; acc += in[i]; }
  if (hi == n && lo <= n) out[n] = acc;
}

// offr[r] = start[r*NB]; offr[NR] = start[NTOT]
__global__ void offr_k(const int* __restrict__ start, int* __restrict__ offr) {
  int t = threadIdx.x;
  if (t < NR) offr[t] = start[t * NB];
  if (t == NR) offr[NR] = start[NTOT];
}

// Place edges: rank via LDS atomic (intra-block), position via scanned start.
__global__ __launch_bounds__(EPB) void place_k(const int* __restrict__ src,
                                               const int* __restrict__ dst,
                                               const int* __restrict__ et,
                                               const int* __restrict__ cnt,
                                               const int* __restrict__ start,
                                               int* __restrict__ es,
                                               int* __restrict__ ed,
                                               float* __restrict__ enorm) {
  __shared__ int lcur[NR];
  int t = threadIdx.x, b = blockIdx.x;
  if (t < NR) lcur[t] = 0;
  __syncthreads();
  int e = b * EPB + t;
  if (e < NE) {
    int r = et[e];
    int d = dst[e];
    int rank = atomicAdd(&lcur[r], 1);
    int p = start[r * NB + b] + rank;
    es[p] = src[e];
    ed[p] = d;
    int c = cnt[(size_t)d * NR + r];
    enorm[p] = 1.0f / (float)(c > 0 ? c : 1);
  }
}

// Sort edge positions p by dst into CSR (nodeoff, plist).
__global__ void plist_k(const int* __restrict__ ed, const int* __restrict__ nodeoff,
                        int* __restrict__ ncur, int* __restrict__ plist) {
  int p = blockIdx.x * 256 + threadIdx.x;
  if (p < NE) {
    int d = ed[p];
    int q = nodeoff[d] + atomicAdd(&ncur[d], 1);
    plist[q] = p;
  }
}

// ---------------------------------------------------------------------------
// MFMA GEMM core (128x128 tile, 4 waves 2x2, 4x4 frags of 16x16x32 bf16,
// split bf16x2: hi*hi + hi*lo + lo*hi)
// ---------------------------------------------------------------------------
#define MFMA_BF16 __builtin_amdgcn_mfma_f32_16x16x32_bf16

template<int K>
__global__ __launch_bounds__(256) void gemm_edge(const float* __restrict__ X,
                                                 const short* __restrict__ Wt,
                                                 const int* __restrict__ es,
                                                 const float* __restrict__ enorm,
                                                 const int* __restrict__ offr,
                                                 float* __restrict__ tmp,
                                                 int half) {
  constexpr int KC = K / 32;
  __shared__ __align__(16) short Ah[4096], Al[4096], Bh[4096], Bl[4096];
  const int t = threadIdx.x;
  const int rel = blockIdx.x / MAX_T2;
  const int tile = blockIdx.x % MAX_T2;
  const int e_lo = offr[rel], e_hi = offr[rel + 1];
  if (e_lo + tile * TE2 >= e_hi) return;
  const short* WtM = Wt + (size_t)(rel * 2 + half) * (2 * KC * 4096);
  const int lane = t & 63, wv = t >> 6;
  const int r = t & 127, cp = t >> 7;
  const int rowb = (wv & 1) * 64, colb = (wv >> 1) * 64;
  const int fo = (((lane & 15) * 64 + (lane >> 4) * 16) ^ ((lane & 7) << 4)) >> 1;

  for (int base = e_lo + tile * TE2; base < e_hi; base += MAX_T2 * TE2) {
    const int nE = min(TE2, e_hi - base);
    const float* xrow = X + (size_t)es[base + ((r < nE) ? r : 0)] * K;
    const float nrm = (r < nE) ? enorm[base + r] : 0.f;
    f32x4 acc[4][4];
#pragma unroll
    for (int f = 0; f < 4; ++f)
#pragma unroll
      for (int n = 0; n < 4; ++n) acc[f][n] = {0.f, 0.f, 0.f, 0.f};

    for (int ks = 0; ks < KC; ++ks) {
#pragma unroll
      for (int j = 0; j < 2; ++j) {
        int ch = wv * 2 + j;
        gl16(WtM + (size_t)ks * 4096 + ch * 512 + lane * 8, &Bh[ch * 512]);
        gl16(WtM + (size_t)(KC + ks) * 4096 + ch * 512 + lane * 8, &Bl[ch * 512]);
      }
#pragma unroll
      for (int j = 0; j < 2; ++j) {
        int c = cp * 2 + j;
        float4 a = *(const float4*)&xrow[ks * 32 + c * 4];
        float4 b = *(const float4*)&xrow[ks * 32 + 16 + c * 4];
        float v[8] = {a.x * nrm, a.y * nrm, a.z * nrm, a.w * nrm,
                      b.x * nrm, b.y * nrm, b.z * nrm, b.w * nrm};
        bf16x8 hv, lv;
#pragma unroll
        for (int i = 0; i < 8; ++i) {
          unsigned short h = f2bf(v[i]);
          hv[i] = (short)h;
          lv[i] = (short)f2bf(v[i] - bf2f(h));
        }
        int ab = (r * 64 + c * 16) ^ ((r & 7) << 4);
        *(bf16x8*)((char*)Ah + ab) = hv;
        *(bf16x8*)((char*)Al + ab) = lv;
      }
      __syncthreads();
      bf16x8 afh[4], afl[4], bfh[4], bfl[4];
#pragma unroll
      for (int f = 0; f < 4; ++f) {
        int o = (rowb + f * 16) * 32 + fo;
        afh[f] = *(const bf16x8*)&Ah[o];
        afl[f] = *(const bf16x8*)&Al[o];
      }
#pragma unroll
      for (int n = 0; n < 4; ++n) {
        int o = (colb + n * 16) * 32 + fo;
        bfh[n] = *(const bf16x8*)&Bh[o];
        bfl[n] = *(const bf16x8*)&Bl[o];
      }
#pragma unroll
      for (int f = 0; f < 4; ++f)
#pragma unroll
        for (int n = 0; n < 4; ++n) {
          acc[f][n] = MFMA_BF16(afh[f], bfh[n], acc[f][n], 0, 0, 0);
          acc[f][n] = MFMA_BF16(afh[f], bfl[n], acc[f][n], 0, 0, 0);
          acc[f][n] = MFMA_BF16(afl[f], bfh[n], acc[f][n], 0, 0, 0);
        }
      __syncthreads();
    }
#pragma unroll
    for (int f = 0; f < 4; ++f) {
      int rb = rowb + f * 16 + (lane >> 4) * 4;
#pragma unroll
      for (int rr = 0; rr < 4; ++rr) {
        int row = rb + rr;
        if (row < nE) {
          float* o = &tmp[(size_t)(base + row) * 128 + colb + (lane & 15)];
#pragma unroll
          for (int n = 0; n < 4; ++n) o[n * 16] = acc[f][n][rr];
        }
      }
    }
  }
}

template<int K>
__global__ __launch_bounds__(256) void gemm_root(const float* __restrict__ X,
                                                 const short* __restrict__ Wtr,
                                                 const float* __restrict__ bias,
                                                 float* __restrict__ out, int M) {
  constexpr int KC = K / 32;
  __shared__ __align__(16) short Ah[4096], Al[4096], Bh[4096], Bl[4096];
  const int t = threadIdx.x;
  const int row0 = blockIdx.x * TE2;
  const int half = blockIdx.y;
  const short* WtM = Wtr + (size_t)half * (2 * KC * 4096);
  const int lane = t & 63, wv = t >> 6;
  const int r = t & 127, cp = t >> 7;
  const int rowb = (wv & 1) * 64, colb = (wv >> 1) * 64;
  const int fo = (((lane & 15) * 64 + (lane >> 4) * 16) ^ ((lane & 7) << 4)) >> 1;

  const int gr = row0 + r;
  const float* xrow = X + (size_t)(gr < M ? gr : 0) * K;
  const float nrm = (gr < M) ? 1.f : 0.f;
  f32x4 acc[4][4];
#pragma unroll
  for (int f = 0; f < 4; ++f)
#pragma unroll
    for (int n = 0; n < 4; ++n) acc[f][n] = {0.f, 0.f, 0.f, 0.f};

  for (int ks = 0; ks < KC; ++ks) {
#pragma unroll
    for (int j = 0; j < 2; ++j) {
      int ch = wv * 2 + j;
      gl16(WtM + (size_t)ks * 4096 + ch * 512 + lane * 8, &Bh[ch * 512]);
      gl16(WtM + (size_t)(KC + ks) * 4096 + ch * 512 + lane * 8, &Bl[ch * 512]);
    }
#pragma unroll
    for (int j = 0; j < 2; ++j) {
      int c = cp * 2 + j;
      float4 a = *(const float4*)&xrow[ks * 32 + c * 4];
      float4 b = *(const float4*)&xrow[ks * 32 + 16 + c * 4];
      float v[8] = {a.x * nrm, a.y * nrm, a.z * nrm, a.w * nrm,
                    b.x * nrm, b.y * nrm, b.z * nrm, b.w * nrm};
      bf16x8 hv, lv;
#pragma unroll
      for (int i = 0; i < 8; ++i) {
        unsigned short h = f2bf(v[i]);
        hv[i] = (short)h;
        lv[i] = (short)f2bf(v[i] - bf2f(h));
      }
      int ab = (r * 64 + c * 16) ^ ((r & 7) << 4);
      *(bf16x8*)((char*)Ah + ab) = hv;
      *(bf16x8*)((char*)Al + ab) = lv;
    }
    __syncthreads();
    bf16x8 afh[4], afl[4], bfh[4], bfl[4];
#pragma unroll
    for (int f = 0; f < 4; ++f) {
      int o = (rowb + f * 16) * 32 + fo;
      afh[f] = *(const bf16x8*)&Ah[o];
      afl[f] = *(const bf16x8*)&Al[o];
    }
#pragma unroll
    for (int n = 0; n < 4; ++n) {
      int o = (colb + n * 16) * 32 + fo;
      bfh[n] = *(const bf16x8*)&Bh[o];
      bfl[n] = *(const bf16x8*)&Bl[o];
    }
#pragma unroll
    for (int f = 0; f < 4; ++f)
#pragma unroll
      for (int n = 0; n < 4; ++n) {
        acc[f][n] = MFMA_BF16(afh[f], bfh[n], acc[f][n], 0, 0, 0);
        acc[f][n] = MFMA_BF16(afh[f], bfl[n], acc[f][n], 0, 0, 0);
        acc[f][n] = MFMA_BF16(afl[f], bfh[n], acc[f][n], 0, 0, 0);
      }
    __syncthreads();
  }
#pragma unroll
  for (int f = 0; f < 4; ++f) {
    int rb = rowb + f * 16 + (lane >> 4) * 4;
#pragma unroll
    for (int rr = 0; rr < 4; ++rr) {
      int row = rb + rr;
      if (row0 + row < M) {
#pragma unroll
        for (int n = 0; n < 4; ++n) {
          int cg = half * 128 + colb + n * 16 + (lane & 15);
          out[(size_t)(row0 + row) * HD + cg] = acc[f][n][rr] + bias[cg];
        }
      }
    }
  }
}

// ---------------------------------------------------------------------------
// Per-node gather-reduce over one 128-col half: h[n][col0..] = relu(h + sum tmp)
// ---------------------------------------------------------------------------
__global__ __launch_bounds__(256) void reduce_k(float* __restrict__ h,
                                                const float* __restrict__ tmp,
                                                const int* __restrict__ nodeoff,
                                                const int* __restrict__ plist,
                                                int col0) {
  int wid = (blockIdx.x * 256 + threadIdx.x) >> 6;
  int lane = threadIdx.x & 63;
  if (wid >= NN) return;
  float* row = h + (size_t)wid * HD + col0 + lane * 2;
  float2 acc = *(float2*)row;
  int lo = nodeoff[wid], hi = nodeoff[wid + 1];
  for (int q = lo; q < hi; ++q) {
    int p = plist[q];
    float2 v = *(const float2*)&tmp[(size_t)p * 128 + lane * 2];
    acc.x += v.x; acc.y += v.y;
  }
  acc.x = fmaxf(acc.x, 0.f);
  acc.y = fmaxf(acc.y, 0.f);
  *(float2*)row = acc;
}

// ---------------------------------------------------------------------------
// Pooling and fused MLP head
// ---------------------------------------------------------------------------
__global__ __launch_bounds__(256) void pool_k(const float* __restrict__ h,
                                              const float* __restrict__ wsw,
                                              const float* __restrict__ wsb,
                                              const int* __restrict__ goff,
                                              float* __restrict__ g) {
  int wid = (blockIdx.x * 256 + threadIdx.x) >> 6;
  int lane = threadIdx.x & 63;
  if (wid >= NG) return;
  float4 w4 = *(const float4*)&wsw[lane * 4];
  float wb = wsb[0];
  float4 acc = make_float4(0.f, 0.f, 0.f, 0.f);
  int lo = goff[wid], hi = goff[wid + 1];
  for (int n = lo; n < hi; ++n) {
    float4 v = *(const float4*)&h[(size_t)n * HD + lane * 4];
    float p = v.x * w4.x + v.y * w4.y + v.z * w4.z + v.w * w4.w;
#pragma unroll
    for (int o = 32; o > 0; o >>= 1) p += __shfl_xor(p, o, 64);
    float gate = 1.f / (1.f + expf(-(p + wb)));
    acc.x += gate * v.x;
    acc.y += gate * v.y;
    acc.z += gate * v.z;
    acc.w += gate * v.w;
  }
  *(float4*)&g[(size_t)wid * HD + lane * 4] = acc;
}

__global__ __launch_bounds__(64) void mlp_k(const float* __restrict__ g,
                                            const float* __restrict__ m1,
                                            const float* __restrict__ mb1,
                                            const float* __restrict__ m2,
                                            const float* __restrict__ mb2,
                                            const float* __restrict__ m3,
                                            const float* __restrict__ mb3,
                                            float* __restrict__ out) {
  __shared__ float sg[HD];
  __shared__ float s1[MH];
  int gr = blockIdx.x;
  int t = threadIdx.x;
  float4 v = *(const float4*)&g[(size_t)gr * HD + t * 4];
  *(float4*)&sg[t * 4] = v;
  __syncthreads();
  float a = mb1[t];
  for (int k = 0; k < HD; ++k) a += sg[k] * m1[k * MH + t];
  a = fmaxf(a, 0.f);
  s1[t] = a;
  __syncthreads();
  float b = mb2[t];
#pragma unroll
  for (int k = 0; k < MH; ++k) b += s1[k] * m2[k * MH + t];
  b = fmaxf(b, 0.f);
  float c = b * m3[t];
#pragma unroll
  for (int o = 32; o > 0; o >>= 1) c += __shfl_xor(c, o, 64);
  if (t == 0) out[gr] = c + mb3[0];
}

// ---------------------------------------------------------------------------
extern "C" void kernel_launch(void* const* d_in, const int* in_sizes, int n_in,
                              void* d_out, int out_size, void* d_ws, size_t ws_size,
                              hipStream_t stream) {
  const float* x = (const float*)d_in[0];
  const int* ei = (const int*)d_in[1];
  const int* etype = (const int*)d_in[2];
  const int* batch = (const int*)d_in[3];
  const float* W1 = (const float*)d_in[4];
  const float* root1 = (const float*)d_in[5];
  const float* b1 = (const float*)d_in[6];
  const float* W2 = (const float*)d_in[7];
  const float* root2 = (const float*)d_in[8];
  const float* b2 = (const float*)d_in[9];
  const float* wsw = (const float*)d_in[10];
  const float* wsb = (const float*)d_in[11];
  const float* m1 = (const float*)d_in[12];
  const float* mb1 = (const float*)d_in[13];
  const float* m2 = (const float*)d_in[14];
  const float* mb2 = (const float*)d_in[15];
  const float* m3 = (const float*)d_in[16];
  const float* mb3 = (const float*)d_in[17];
  const int* esrc = ei;
  const int* edst = ei + NE;

  constexpr int KC1 = KP / 32;  // 3
  constexpr int KC2 = HD / 32;  // 8

  // Workspace layout (256B aligned). Aliases:
  //   cnt (NN*NR ints)   over tmp head (dead before tmp written)
  //   xp / wt1 / wtr1    inside h2     (dead before L2 root writes h2)
  char* ws = (char*)d_ws;
  size_t off = 0;
  auto alloc = [&](size_t bytes) {
    size_t o = off;
    off = (off + bytes + 255) & ~(size_t)255;
    return o;
  };
  size_t o_tmp = alloc((size_t)NE * 128 * 4);      // 76.8 MB
  size_t o_h1 = alloc((size_t)NN * HD * 4);        // 51.2 MB
  size_t o_h2x = alloc((size_t)NN * HD * 4);       // 51.2 MB (h2 | xp+wt1+wtr1)
  size_t o_g = alloc((size_t)NG * HD * 4);
  size_t o_es = alloc((size_t)NE * 4);
  size_t o_ed = alloc((size_t)NE * 4);
  size_t o_enorm = alloc((size_t)NE * 4);
  size_t o_plist = alloc((size_t)NE * 4);
  size_t o_nodeoff = alloc((NN + 1) * 4);
  size_t o_goff = alloc((NG + 1) * 4);
  size_t o_offr = alloc((NR + 1) * 4);
  size_t o_bh = alloc((size_t)NTOT * 4);           // 38 KB
  size_t o_start = alloc((size_t)(NTOT + 1) * 4);  // 38 KB
  size_t o_wt2 = alloc((size_t)NR * 4 * KC2 * 4096 * 2);  // 17.04 MB
  size_t o_wtr2 = alloc((size_t)4 * KC2 * 4096 * 2);      // 262 KB
  size_t zs = off;  // zero region
  size_t o_ndeg = alloc((size_t)NN * 4);
  size_t o_ncur = alloc((size_t)NN * 4);
  size_t o_ghist = alloc((size_t)NG * 4);
  size_t ze = off;
  if (ws_size < off) return;

  float* tmp = (float*)(ws + o_tmp);
  int* cnt = (int*)(ws + o_tmp);                   // alias
  float* h1 = (float*)(ws + o_h1);
  float* h2 = (float*)(ws + o_h2x);
  float* xp = (float*)(ws + o_h2x);                // alias (19.2 MB)
  short* wt1 = (short*)(ws + o_h2x + 19200000);    // alias (6.39 MB)
  short* wtr1 = (short*)(ws + o_h2x + 19200000 + 6389760);  // alias (98 KB)
  float* g = (float*)(ws + o_g);
  int* es = (int*)(ws + o_es);
  int* ed = (int*)(ws + o_ed);
  float* enorm = (float*)(ws + o_enorm);
  int* plist = (int*)(ws + o_plist);
  int* nodeoff = (int*)(ws + o_nodeoff);
  int* goff = (int*)(ws + o_goff);
  int* offr = (int*)(ws + o_offr);
  int* bh = (int*)(ws + o_bh);
  int* start = (int*)(ws + o_start);
  short* wt2 = (short*)(ws + o_wt2);
  short* wtr2 = (short*)(ws + o_wtr2);
  int* ndeg = (int*)(ws + o_ndeg);
  int* ncur = (int*)(ws + o_ncur);
  int* ghist = (int*)(ws + o_ghist);
  float* outp = (float*)d_out;

  hipMemsetAsync(ws + o_tmp, 0, (size_t)NN * NR * 4, stream);  // cnt
  hipMemsetAsync(ws + zs, 0, ze - zs, stream);

  // Weight prep + padded x
  padx_k<<<(NN * KP + 255) / 256, 256, 0, stream>>>(x, xp);
  build_wt<<<(NR * 2 * KC1 * 512 + 255) / 256, 256, 0, stream>>>(W1, wt1, FIN, KC1, NR);
  build_wt<<<(2 * KC1 * 512 + 255) / 256, 256, 0, stream>>>(root1, wtr1, FIN, KC1, 1);
  build_wt<<<(NR * 2 * KC2 * 512 + 255) / 256, 256, 0, stream>>>(W2, wt2, HD, KC2, NR);
  build_wt<<<(2 * KC2 * 512 + 255) / 256, 256, 0, stream>>>(root2, wtr2, HD, KC2, 1);

  // Edge preprocessing — contention-free sort
  count_k<<<(NE + 255) / 256, 256, 0, stream>>>(edst, etype, cnt, ndeg);
  gcount_k<<<(NN + 255) / 256, 256, 0, stream>>>(batch, ghist);
  histblk_k<<<NB, EPB, 0, stream>>>(etype, bh);
  scan_k<<<1, 1024, 0, stream>>>(bh, start, NTOT);
  offr_k<<<1, 128, 0, stream>>>(start, offr);
  scan_k<<<1, 1024, 0, stream>>>(ndeg, nodeoff, NN);
  scan_k<<<1, 1024, 0, stream>>>(ghist, goff, NG);
  place_k<<<NB, EPB, 0, stream>>>(esrc, edst, etype, cnt, start, es, ed, enorm);
  plist_k<<<(NE + 255) / 256, 256, 0, stream>>>(ed, nodeoff, ncur, plist);

  const dim3 gRoot((NN + TE2 - 1) / TE2, 2);
  const int gEdge = NR * MAX_T2;
  const int nRed = (NN * 64 + 255) / 256;

  // Layer 1
  gemm_root<KP><<<gRoot, 256, 0, stream>>>(xp, wtr1, b1, h1, NN);
  gemm_edge<KP><<<gEdge, 256, 0, stream>>>(xp, wt1, es, enorm, offr, tmp, 0);
  reduce_k<<<nRed, 256, 0, stream>>>(h1, tmp, nodeoff, plist, 0);
  gemm_edge<KP><<<gEdge, 256, 0, stream>>>(xp, wt1, es, enorm, offr, tmp, 1);
  reduce_k<<<nRed, 256, 0, stream>>>(h1, tmp, nodeoff, plist, 128);

  // Layer 2 (xp/wt1/wtr1 dead; h2 written by root)
  gemm_root<HD><<<gRoot, 256, 0, stream>>>(h1, wtr2, b2, h2, NN);
  gemm_edge<HD><<<gEdge, 256, 0, stream>>>(h1, wt2, es, enorm, offr, tmp, 0);
  reduce_k<<<nRed, 256, 0, stream>>>(h2, tmp, nodeoff, plist, 0);
  gemm_edge<HD><<<gEdge, 256, 0, stream>>>(h1, wt2, es, enorm, offr, tmp, 1);
  reduce_k<<<nRed, 256, 0, stream>>>(h2, tmp, nodeoff, plist, 128);

  // Pooling + MLP head
  pool_k<<<(NG * 64 + 255) / 256, 256, 0, stream>>>(h2, wsw, wsb, goff, g);
  mlp_k<<<NG, 64, 0, stream>>>(g, m1, mb1, m2, mb2, m3, mb3, outp);
}

// Round 7
// 588.244 us; speedup vs baseline: 4.1199x; 1.1012x over previous
//
#include <hip/hip_runtime.h>
#include <hip/hip_bf16.h>

// Problem constants
#define NN 50000
#define NE 150000
#define NR 65
#define NG 2000
#define FIN 74
#define KP 96      // layer-1 K padded (zero-filled)
#define HD 256
#define MH 64

#define TE2 128    // rows per GEMM tile
#define MAX_T2 20  // tile slots per relation (loop covers overflow)

#define EPB 1024                    // edges per sort block
#define NB ((NE + EPB - 1) / EPB)   // 147
#define NTOT (NR * NB)              // 9555

#define SCHUNK 512                  // elements per scan block

typedef __attribute__((ext_vector_type(8))) short bf16x8;
typedef __attribute__((ext_vector_type(4))) float f32x4;

__device__ __forceinline__ unsigned short f2bf(float x) {
  unsigned u = __builtin_bit_cast(unsigned, x);
  u += 0x7FFF + ((u >> 16) & 1);  // RNE
  return (unsigned short)(u >> 16);
}
__device__ __forceinline__ float bf2f(unsigned short h) {
  unsigned u = (unsigned)h << 16;
  return __builtin_bit_cast(float, u);
}

__device__ __forceinline__ void gl16(const short* g, short* lds) {
  __builtin_amdgcn_global_load_lds(
      (const __attribute__((address_space(1))) void*)g,
      (__attribute__((address_space(3))) void*)lds, 16, 0, 0);
}

// ---------------------------------------------------------------------------
// Weight prep: fp32 W[nmat][Kin][256] -> bf16 hi/lo planes, transposed to
// [mat][half][plane][kstep][8 col-groups][1KB], MFMA stacked-K perm + XOR
// bank-swizzle baked in so GEMM stages it with linear global_load_lds.
// ---------------------------------------------------------------------------
__global__ void build_wt(const float* __restrict__ Wsrc, short* __restrict__ dst,
                         int Kin, int KC, int nmat) {
  int tid = blockIdx.x * 256 + threadIdx.x;
  int total = nmat * 2 * KC * 512;
  if (tid >= total) return;
  int c = tid & 3;
  int colin = (tid >> 2) & 15;
  int grp = (tid >> 6) & 7;
  int rem = tid >> 9;
  int ks = rem % KC;  rem /= KC;
  int half = rem & 1;
  int mat = rem >> 1;
  int col = half * 128 + grp * 16 + colin;
  bf16x8 hv, lv;
#pragma unroll
  for (int i = 0; i < 8; ++i) {
    int kk = (i < 4) ? (c * 4 + i) : (16 + c * 4 + (i - 4));
    int k = ks * 32 + kk;
    float v = (k < Kin) ? Wsrc[((size_t)mat * Kin + k) * HD + col] : 0.f;
    unsigned short h = f2bf(v);
    hv[i] = (short)h;
    lv[i] = (short)f2bf(v - bf2f(h));
  }
  int byteoff = grp * 1024 + ((colin * 64 + c * 16) ^ ((colin & 7) << 4));
  char* basehi = (char*)dst + ((size_t)((mat * 2 + half) * 2 + 0) * KC) * 8192;
  char* baselo = (char*)dst + ((size_t)((mat * 2 + half) * 2 + 1) * KC) * 8192;
  *(bf16x8*)(basehi + (size_t)ks * 8192 + byteoff) = hv;
  *(bf16x8*)(baselo + (size_t)ks * 8192 + byteoff) = lv;
}

// x [NN][74] -> xp [NN][96] zero-padded
__global__ void padx_k(const float* __restrict__ x, float* __restrict__ xp) {
  int i = blockIdx.x * 256 + threadIdx.x;
  if (i < NN * KP) {
    int n = i / KP, k = i - n * KP;
    xp[i] = (k < FIN) ? x[(size_t)n * FIN + k] : 0.f;
  }
}

// ---------------------------------------------------------------------------
// Edge preprocessing — contention-free counting sort by relation.
// ---------------------------------------------------------------------------
__global__ void count_k(const int* __restrict__ dst, const int* __restrict__ et,
                        int* __restrict__ cnt, int* __restrict__ ndeg) {
  int e = blockIdx.x * 256 + threadIdx.x;
  if (e < NE) {
    atomicAdd(&cnt[(size_t)dst[e] * NR + et[e]], 1);
    atomicAdd(&ndeg[dst[e]], 1);
  }
}

__global__ void gcount_k(const int* __restrict__ batch, int* __restrict__ ghist) {
  int i = blockIdx.x * 256 + threadIdx.x;
  if (i < NN) atomicAdd(&ghist[batch[i]], 1);
}

// Per-block relation histogram -> bh[r*NB + b]
__global__ __launch_bounds__(EPB) void histblk_k(const int* __restrict__ et,
                                                 int* __restrict__ bh) {
  __shared__ int lh[NR];
  int t = threadIdx.x, b = blockIdx.x;
  if (t < NR) lh[t] = 0;
  __syncthreads();
  int e = b * EPB + t;
  if (e < NE) atomicAdd(&lh[et[e]], 1);
  __syncthreads();
  if (t < NR) bh[t * NB + b] = lh[t];
}

// ---------------------------------------------------------------------------
// Hierarchical exclusive scan: psum (per-512-chunk sums) -> scanb (1 block
// over <=256 chunk sums) -> apply (chunk-local scan + base). out[n] = total.
// ---------------------------------------------------------------------------
__global__ __launch_bounds__(256) void psum_k(const int* __restrict__ in,
                                              int* __restrict__ bsum, int n) {
  __shared__ int ws4[4];
  int b = blockIdx.x, t = threadIdx.x;
  int base = b * SCHUNK;
  int s = 0;
#pragma unroll
  for (int i = 0; i < SCHUNK / 256; ++i) {
    int g = base + t + i * 256;
    if (g < n) s += in[g];
  }
#pragma unroll
  for (int o = 32; o > 0; o >>= 1) s += __shfl_down(s, o, 64);
  if ((t & 63) == 0) ws4[t >> 6] = s;
  __syncthreads();
  if (t == 0) bsum[b] = ws4[0] + ws4[1] + ws4[2] + ws4[3];
}

__global__ __launch_bounds__(256) void scanb_k(int* __restrict__ bsum, int nb) {
  __shared__ int ld[256];
  int t = threadIdx.x;
  int v = (t < nb) ? bsum[t] : 0;
  ld[t] = v;
  __syncthreads();
  int acc = v;
#pragma unroll
  for (int o = 1; o < 256; o <<= 1) {
    int u = (t >= o) ? ld[t - o] : 0;
    __syncthreads();
    acc += u;
    ld[t] = acc;
    __syncthreads();
  }
  if (t < nb) bsum[t] = acc - v;  // exclusive
  if (t == nb - 1) bsum[nb] = acc;  // total
}

__global__ __launch_bounds__(256) void apply_k(const int* __restrict__ in,
                                               const int* __restrict__ bsum,
                                               int* __restrict__ out, int n) {
  __shared__ int ld[256];
  int b = blockIdx.x, t = threadIdx.x;
  int base = b * SCHUNK + t * 2;
  int v0 = (base < n) ? in[base] : 0;
  int v1 = (base + 1 < n) ? in[base + 1] : 0;
  int ps = v0 + v1;
  ld[t] = ps;
  __syncthreads();
  int acc = ps;
#pragma unroll
  for (int o = 1; o < 256; o <<= 1) {
    int u = (t >= o) ? ld[t - o] : 0;
    __syncthreads();
    acc += u;
    ld[t] = acc;
    __syncthreads();
  }
  int excl = acc - ps + bsum[b];
  if (base < n) out[base] = excl;
  if (base + 1 < n) out[base + 1] = excl + v0;
  if (base == n - 1) out[n] = excl + v0;
  else if (base + 1 == n - 1) out[n] = excl + v0 + v1;
}

// offr[r] = start[r*NB]; offr[NR] = start[NTOT]
__global__ void offr_k(const int* __restrict__ start, int* __restrict__ offr) {
  int t = threadIdx.x;
  if (t < NR) offr[t] = start[t * NB];
  if (t == NR) offr[NR] = start[NTOT];
}

// Place edges: rank via LDS atomic (intra-block), position via scanned start.
__global__ __launch_bounds__(EPB) void place_k(const int* __restrict__ src,
                                               const int* __restrict__ dst,
                                               const int* __restrict__ et,
                                               const int* __restrict__ cnt,
                                               const int* __restrict__ start,
                                               int* __restrict__ es,
                                               int* __restrict__ ed,
                                               float* __restrict__ enorm) {
  __shared__ int lcur[NR];
  int t = threadIdx.x, b = blockIdx.x;
  if (t < NR) lcur[t] = 0;
  __syncthreads();
  int e = b * EPB + t;
  if (e < NE) {
    int r = et[e];
    int d = dst[e];
    int rank = atomicAdd(&lcur[r], 1);
    int p = start[r * NB + b] + rank;
    es[p] = src[e];
    ed[p] = d;
    int c = cnt[(size_t)d * NR + r];
    enorm[p] = 1.0f / (float)(c > 0 ? c : 1);
  }
}

// Sort edge positions p by dst into CSR (nodeoff, plist).
__global__ void plist_k(const int* __restrict__ ed, const int* __restrict__ nodeoff,
                        int* __restrict__ ncur, int* __restrict__ plist) {
  int p = blockIdx.x * 256 + threadIdx.x;
  if (p < NE) {
    int d = ed[p];
    int q = nodeoff[d] + atomicAdd(&ncur[d], 1);
    plist[q] = p;
  }
}

// ---------------------------------------------------------------------------
// MFMA GEMM core (128x128 tile, 4 waves 2x2, 4x4 frags of 16x16x32 bf16,
// split bf16x2: hi*hi + hi*lo + lo*hi)
// ---------------------------------------------------------------------------
#define MFMA_BF16 __builtin_amdgcn_mfma_f32_16x16x32_bf16

template<int K>
__global__ __launch_bounds__(256) void gemm_edge(const float* __restrict__ X,
                                                 const short* __restrict__ Wt,
                                                 const int* __restrict__ es,
                                                 const float* __restrict__ enorm,
                                                 const int* __restrict__ offr,
                                                 float* __restrict__ tmp,
                                                 int half) {
  constexpr int KC = K / 32;
  __shared__ __align__(16) short Ah[4096], Al[4096], Bh[4096], Bl[4096];
  const int t = threadIdx.x;
  const int rel = blockIdx.x / MAX_T2;
  const int tile = blockIdx.x % MAX_T2;
  const int e_lo = offr[rel], e_hi = offr[rel + 1];
  if (e_lo + tile * TE2 >= e_hi) return;
  const short* WtM = Wt + (size_t)(rel * 2 + half) * (2 * KC * 4096);
  const int lane = t & 63, wv = t >> 6;
  const int r = t & 127, cp = t >> 7;
  const int rowb = (wv & 1) * 64, colb = (wv >> 1) * 64;
  const int fo = (((lane & 15) * 64 + (lane >> 4) * 16) ^ ((lane & 7) << 4)) >> 1;

  for (int base = e_lo + tile * TE2; base < e_hi; base += MAX_T2 * TE2) {
    const int nE = min(TE2, e_hi - base);
    const float* xrow = X + (size_t)es[base + ((r < nE) ? r : 0)] * K;
    const float nrm = (r < nE) ? enorm[base + r] : 0.f;
    f32x4 acc[4][4];
#pragma unroll
    for (int f = 0; f < 4; ++f)
#pragma unroll
      for (int n = 0; n < 4; ++n) acc[f][n] = {0.f, 0.f, 0.f, 0.f};

    for (int ks = 0; ks < KC; ++ks) {
#pragma unroll
      for (int j = 0; j < 2; ++j) {
        int ch = wv * 2 + j;
        gl16(WtM + (size_t)ks * 4096 + ch * 512 + lane * 8, &Bh[ch * 512]);
        gl16(WtM + (size_t)(KC + ks) * 4096 + ch * 512 + lane * 8, &Bl[ch * 512]);
      }
#pragma unroll
      for (int j = 0; j < 2; ++j) {
        int c = cp * 2 + j;
        float4 a = *(const float4*)&xrow[ks * 32 + c * 4];
        float4 b = *(const float4*)&xrow[ks * 32 + 16 + c * 4];
        float v[8] = {a.x * nrm, a.y * nrm, a.z * nrm, a.w * nrm,
                      b.x * nrm, b.y * nrm, b.z * nrm, b.w * nrm};
        bf16x8 hv, lv;
#pragma unroll
        for (int i = 0; i < 8; ++i) {
          unsigned short h = f2bf(v[i]);
          hv[i] = (short)h;
          lv[i] = (short)f2bf(v[i] - bf2f(h));
        }
        int ab = (r * 64 + c * 16) ^ ((r & 7) << 4);
        *(bf16x8*)((char*)Ah + ab) = hv;
        *(bf16x8*)((char*)Al + ab) = lv;
      }
      __syncthreads();
      bf16x8 afh[4], afl[4], bfh[4], bfl[4];
#pragma unroll
      for (int f = 0; f < 4; ++f) {
        int o = (rowb + f * 16) * 32 + fo;
        afh[f] = *(const bf16x8*)&Ah[o];
        afl[f] = *(const bf16x8*)&Al[o];
      }
#pragma unroll
      for (int n = 0; n < 4; ++n) {
        int o = (colb + n * 16) * 32 + fo;
        bfh[n] = *(const bf16x8*)&Bh[o];
        bfl[n] = *(const bf16x8*)&Bl[o];
      }
#pragma unroll
      for (int f = 0; f < 4; ++f)
#pragma unroll
        for (int n = 0; n < 4; ++n) {
          acc[f][n] = MFMA_BF16(afh[f], bfh[n], acc[f][n], 0, 0, 0);
          acc[f][n] = MFMA_BF16(afh[f], bfl[n], acc[f][n], 0, 0, 0);
          acc[f][n] = MFMA_BF16(afl[f], bfh[n], acc[f][n], 0, 0, 0);
        }
      __syncthreads();
    }
#pragma unroll
    for (int f = 0; f < 4; ++f) {
      int rb = rowb + f * 16 + (lane >> 4) * 4;
#pragma unroll
      for (int rr = 0; rr < 4; ++rr) {
        int row = rb + rr;
        if (row < nE) {
          float* o = &tmp[(size_t)(base + row) * 128 + colb + (lane & 15)];
#pragma unroll
          for (int n = 0; n < 4; ++n) o[n * 16] = acc[f][n][rr];
        }
      }
    }
  }
}

template<int K>
__global__ __launch_bounds__(256) void gemm_root(const float* __restrict__ X,
                                                 const short* __restrict__ Wtr,
                                                 const float* __restrict__ bias,
                                                 float* __restrict__ out, int M) {
  constexpr int KC = K / 32;
  __shared__ __align__(16) short Ah[4096], Al[4096], Bh[4096], Bl[4096];
  const int t = threadIdx.x;
  const int row0 = blockIdx.x * TE2;
  const int half = blockIdx.y;
  const short* WtM = Wtr + (size_t)half * (2 * KC * 4096);
  const int lane = t & 63, wv = t >> 6;
  const int r = t & 127, cp = t >> 7;
  const int rowb = (wv & 1) * 64, colb = (wv >> 1) * 64;
  const int fo = (((lane & 15) * 64 + (lane >> 4) * 16) ^ ((lane & 7) << 4)) >> 1;

  const int gr = row0 + r;
  const float* xrow = X + (size_t)(gr < M ? gr : 0) * K;
  const float nrm = (gr < M) ? 1.f : 0.f;
  f32x4 acc[4][4];
#pragma unroll
  for (int f = 0; f < 4; ++f)
#pragma unroll
    for (int n = 0; n < 4; ++n) acc[f][n] = {0.f, 0.f, 0.f, 0.f};

  for (int ks = 0; ks < KC; ++ks) {
#pragma unroll
    for (int j = 0; j < 2; ++j) {
      int ch = wv * 2 + j;
      gl16(WtM + (size_t)ks * 4096 + ch * 512 + lane * 8, &Bh[ch * 512]);
      gl16(WtM + (size_t)(KC + ks) * 4096 + ch * 512 + lane * 8, &Bl[ch * 512]);
    }
#pragma unroll
    for (int j = 0; j < 2; ++j) {
      int c = cp * 2 + j;
      float4 a = *(const float4*)&xrow[ks * 32 + c * 4];
      float4 b = *(const float4*)&xrow[ks * 32 + 16 + c * 4];
      float v[8] = {a.x * nrm, a.y * nrm, a.z * nrm, a.w * nrm,
                    b.x * nrm, b.y * nrm, b.z * nrm, b.w * nrm};
      bf16x8 hv, lv;
#pragma unroll
      for (int i = 0; i < 8; ++i) {
        unsigned short h = f2bf(v[i]);
        hv[i] = (short)h;
        lv[i] = (short)f2bf(v[i] - bf2f(h));
      }
      int ab = (r * 64 + c * 16) ^ ((r & 7) << 4);
      *(bf16x8*)((char*)Ah + ab) = hv;
      *(bf16x8*)((char*)Al + ab) = lv;
    }
    __syncthreads();
    bf16x8 afh[4], afl[4], bfh[4], bfl[4];
#pragma unroll
    for (int f = 0; f < 4; ++f) {
      int o = (rowb + f * 16) * 32 + fo;
      afh[f] = *(const bf16x8*)&Ah[o];
      afl[f] = *(const bf16x8*)&Al[o];
    }
#pragma unroll
    for (int n = 0; n < 4; ++n) {
      int o = (colb + n * 16) * 32 + fo;
      bfh[n] = *(const bf16x8*)&Bh[o];
      bfl[n] = *(const bf16x8*)&Bl[o];
    }
#pragma unroll
    for (int f = 0; f < 4; ++f)
#pragma unroll
      for (int n = 0; n < 4; ++n) {
        acc[f][n] = MFMA_BF16(afh[f], bfh[n], acc[f][n], 0, 0, 0);
        acc[f][n] = MFMA_BF16(afh[f], bfl[n], acc[f][n], 0, 0, 0);
        acc[f][n] = MFMA_BF16(afl[f], bfh[n], acc[f][n], 0, 0, 0);
      }
    __syncthreads();
  }
#pragma unroll
  for (int f = 0; f < 4; ++f) {
    int rb = rowb + f * 16 + (lane >> 4) * 4;
#pragma unroll
    for (int rr = 0; rr < 4; ++rr) {
      int row = rb + rr;
      if (row0 + row < M) {
#pragma unroll
        for (int n = 0; n < 4; ++n) {
          int cg = half * 128 + colb + n * 16 + (lane & 15);
          out[(size_t)(row0 + row) * HD + cg] = acc[f][n][rr] + bias[cg];
        }
      }
    }
  }
}

// ---------------------------------------------------------------------------
// Per-node gather-reduce over one 128-col half: h[n][col0..] = relu(h + sum tmp)
// ---------------------------------------------------------------------------
__global__ __launch_bounds__(256) void reduce_k(float* __restrict__ h,
                                                const float* __restrict__ tmp,
                                                const int* __restrict__ nodeoff,
                                                const int* __restrict__ plist,
                                                int col0) {
  int wid = (blockIdx.x * 256 + threadIdx.x) >> 6;
  int lane = threadIdx.x & 63;
  if (wid >= NN) return;
  float* row = h + (size_t)wid * HD + col0 + lane * 2;
  float2 acc = *(float2*)row;
  int lo = nodeoff[wid], hi = nodeoff[wid + 1];
  for (int q = lo; q < hi; ++q) {
    int p = plist[q];
    float2 v = *(const float2*)&tmp[(size_t)p * 128 + lane * 2];
    acc.x += v.x; acc.y += v.y;
  }
  acc.x = fmaxf(acc.x, 0.f);
  acc.y = fmaxf(acc.y, 0.f);
  *(float2*)row = acc;
}

// ---------------------------------------------------------------------------
// Pooling and fused MLP head
// ---------------------------------------------------------------------------
__global__ __launch_bounds__(256) void pool_k(const float* __restrict__ h,
                                              const float* __restrict__ wsw,
                                              const float* __restrict__ wsb,
                                              const int* __restrict__ goff,
                                              float* __restrict__ g) {
  int wid = (blockIdx.x * 256 + threadIdx.x) >> 6;
  int lane = threadIdx.x & 63;
  if (wid >= NG) return;
  float4 w4 = *(const float4*)&wsw[lane * 4];
  float wb = wsb[0];
  float4 acc = make_float4(0.f, 0.f, 0.f, 0.f);
  int lo = goff[wid], hi = goff[wid + 1];
  for (int n = lo; n < hi; ++n) {
    float4 v = *(const float4*)&h[(size_t)n * HD + lane * 4];
    float p = v.x * w4.x + v.y * w4.y + v.z * w4.z + v.w * w4.w;
#pragma unroll
    for (int o = 32; o > 0; o >>= 1) p += __shfl_xor(p, o, 64);
    float gate = 1.f / (1.f + expf(-(p + wb)));
    acc.x += gate * v.x;
    acc.y += gate * v.y;
    acc.z += gate * v.z;
    acc.w += gate * v.w;
  }
  *(float4*)&g[(size_t)wid * HD + lane * 4] = acc;
}

__global__ __launch_bounds__(64) void mlp_k(const float* __restrict__ g,
                                            const float* __restrict__ m1,
                                            const float* __restrict__ mb1,
                                            const float* __restrict__ m2,
                                            const float* __restrict__ mb2,
                                            const float* __restrict__ m3,
                                            const float* __restrict__ mb3,
                                            float* __restrict__ out) {
  __shared__ float sg[HD];
  __shared__ float s1[MH];
  int gr = blockIdx.x;
  int t = threadIdx.x;
  float4 v = *(const float4*)&g[(size_t)gr * HD + t * 4];
  *(float4*)&sg[t * 4] = v;
  __syncthreads();
  float a = mb1[t];
  for (int k = 0; k < HD; ++k) a += sg[k] * m1[k * MH + t];
  a = fmaxf(a, 0.f);
  s1[t] = a;
  __syncthreads();
  float b = mb2[t];
#pragma unroll
  for (int k = 0; k < MH; ++k) b += s1[k] * m2[k * MH + t];
  b = fmaxf(b, 0.f);
  float c = b * m3[t];
#pragma unroll
  for (int o = 32; o > 0; o >>= 1) c += __shfl_xor(c, o, 64);
  if (t == 0) out[gr] = c + mb3[0];
}

// ---------------------------------------------------------------------------
extern "C" void kernel_launch(void* const* d_in, const int* in_sizes, int n_in,
                              void* d_out, int out_size, void* d_ws, size_t ws_size,
                              hipStream_t stream) {
  const float* x = (const float*)d_in[0];
  const int* ei = (const int*)d_in[1];
  const int* etype = (const int*)d_in[2];
  const int* batch = (const int*)d_in[3];
  const float* W1 = (const float*)d_in[4];
  const float* root1 = (const float*)d_in[5];
  const float* b1 = (const float*)d_in[6];
  const float* W2 = (const float*)d_in[7];
  const float* root2 = (const float*)d_in[8];
  const float* b2 = (const float*)d_in[9];
  const float* wsw = (const float*)d_in[10];
  const float* wsb = (const float*)d_in[11];
  const float* m1 = (const float*)d_in[12];
  const float* mb1 = (const float*)d_in[13];
  const float* m2 = (const float*)d_in[14];
  const float* mb2 = (const float*)d_in[15];
  const float* m3 = (const float*)d_in[16];
  const float* mb3 = (const float*)d_in[17];
  const int* esrc = ei;
  const int* edst = ei + NE;

  constexpr int KC1 = KP / 32;  // 3
  constexpr int KC2 = HD / 32;  // 8
  const int nbN = (NN + SCHUNK - 1) / SCHUNK;     // 98
  const int nbT = (NTOT + SCHUNK - 1) / SCHUNK;   // 19
  const int nbG = (NG + SCHUNK - 1) / SCHUNK;     // 4

  // Workspace layout (256B aligned). Aliases:
  //   cnt (NN*NR ints)   over tmp head (dead before tmp written)
  //   xp / wt1 / wtr1    inside h2     (dead before L2 root writes h2)
  char* ws = (char*)d_ws;
  size_t off = 0;
  auto alloc = [&](size_t bytes) {
    size_t o = off;
    off = (off + bytes + 255) & ~(size_t)255;
    return o;
  };
  size_t o_tmp = alloc((size_t)NE * 128 * 4);      // 76.8 MB
  size_t o_h1 = alloc((size_t)NN * HD * 4);        // 51.2 MB
  size_t o_h2x = alloc((size_t)NN * HD * 4);       // 51.2 MB (h2 | xp+wt1+wtr1)
  size_t o_g = alloc((size_t)NG * HD * 4);
  size_t o_es = alloc((size_t)NE * 4);
  size_t o_ed = alloc((size_t)NE * 4);
  size_t o_enorm = alloc((size_t)NE * 4);
  size_t o_plist = alloc((size_t)NE * 4);
  size_t o_nodeoff = alloc((NN + 1) * 4);
  size_t o_goff = alloc((NG + 1) * 4);
  size_t o_offr = alloc((NR + 1) * 4);
  size_t o_bh = alloc((size_t)NTOT * 4);
  size_t o_start = alloc((size_t)(NTOT + 1) * 4);
  size_t o_bsN = alloc((size_t)(nbN + 1) * 4);
  size_t o_bsT = alloc((size_t)(nbT + 1) * 4);
  size_t o_bsG = alloc((size_t)(nbG + 1) * 4);
  size_t o_wt2 = alloc((size_t)NR * 4 * KC2 * 4096 * 2);  // 17.04 MB
  size_t o_wtr2 = alloc((size_t)4 * KC2 * 4096 * 2);      // 262 KB
  size_t zs = off;  // zero region
  size_t o_ndeg = alloc((size_t)NN * 4);
  size_t o_ncur = alloc((size_t)NN * 4);
  size_t o_ghist = alloc((size_t)NG * 4);
  size_t ze = off;
  if (ws_size < off) return;

  float* tmp = (float*)(ws + o_tmp);
  int* cnt = (int*)(ws + o_tmp);                   // alias
  float* h1 = (float*)(ws + o_h1);
  float* h2 = (float*)(ws + o_h2x);
  float* xp = (float*)(ws + o_h2x);                // alias (19.2 MB)
  short* wt1 = (short*)(ws + o_h2x + 19200000);    // alias (6.39 MB)
  short* wtr1 = (short*)(ws + o_h2x + 19200000 + 6389760);  // alias (98 KB)
  float* g = (float*)(ws + o_g);
  int* es = (int*)(ws + o_es);
  int* ed = (int*)(ws + o_ed);
  float* enorm = (float*)(ws + o_enorm);
  int* plist = (int*)(ws + o_plist);
  int* nodeoff = (int*)(ws + o_nodeoff);
  int* goff = (int*)(ws + o_goff);
  int* offr = (int*)(ws + o_offr);
  int* bh = (int*)(ws + o_bh);
  int* start = (int*)(ws + o_start);
  int* bsN = (int*)(ws + o_bsN);
  int* bsT = (int*)(ws + o_bsT);
  int* bsG = (int*)(ws + o_bsG);
  short* wt2 = (short*)(ws + o_wt2);
  short* wtr2 = (short*)(ws + o_wtr2);
  int* ndeg = (int*)(ws + o_ndeg);
  int* ncur = (int*)(ws + o_ncur);
  int* ghist = (int*)(ws + o_ghist);
  float* outp = (float*)d_out;

  hipMemsetAsync(ws + o_tmp, 0, (size_t)NN * NR * 4, stream);  // cnt
  hipMemsetAsync(ws + zs, 0, ze - zs, stream);

  // Weight prep + padded x
  padx_k<<<(NN * KP + 255) / 256, 256, 0, stream>>>(x, xp);
  build_wt<<<(NR * 2 * KC1 * 512 + 255) / 256, 256, 0, stream>>>(W1, wt1, FIN, KC1, NR);
  build_wt<<<(2 * KC1 * 512 + 255) / 256, 256, 0, stream>>>(root1, wtr1, FIN, KC1, 1);
  build_wt<<<(NR * 2 * KC2 * 512 + 255) / 256, 256, 0, stream>>>(W2, wt2, HD, KC2, NR);
  build_wt<<<(2 * KC2 * 512 + 255) / 256, 256, 0, stream>>>(root2, wtr2, HD, KC2, 1);

  // Edge preprocessing — contention-free sort + hierarchical scans
  count_k<<<(NE + 255) / 256, 256, 0, stream>>>(edst, etype, cnt, ndeg);
  gcount_k<<<(NN + 255) / 256, 256, 0, stream>>>(batch, ghist);
  histblk_k<<<NB, EPB, 0, stream>>>(etype, bh);

  psum_k<<<nbT, 256, 0, stream>>>(bh, bsT, NTOT);
  scanb_k<<<1, 256, 0, stream>>>(bsT, nbT);
  apply_k<<<nbT, 256, 0, stream>>>(bh, bsT, start, NTOT);
  offr_k<<<1, 128, 0, stream>>>(start, offr);

  psum_k<<<nbN, 256, 0, stream>>>(ndeg, bsN, NN);
  scanb_k<<<1, 256, 0, stream>>>(bsN, nbN);
  apply_k<<<nbN, 256, 0, stream>>>(ndeg, bsN, nodeoff, NN);

  psum_k<<<nbG, 256, 0, stream>>>(ghist, bsG, NG);
  scanb_k<<<1, 256, 0, stream>>>(bsG, nbG);
  apply_k<<<nbG, 256, 0, stream>>>(ghist, bsG, goff, NG);

  place_k<<<NB, EPB, 0, stream>>>(esrc, edst, etype, cnt, start, es, ed, enorm);
  plist_k<<<(NE + 255) / 256, 256, 0, stream>>>(ed, nodeoff, ncur, plist);

  const dim3 gRoot((NN + TE2 - 1) / TE2, 2);
  const int gEdge = NR * MAX_T2;
  const int nRed = (NN * 64 + 255) / 256;

  // Layer 1
  gemm_root<KP><<<gRoot, 256, 0, stream>>>(xp, wtr1, b1, h1, NN);
  gemm_edge<KP><<<gEdge, 256, 0, stream>>>(xp, wt1, es, enorm, offr, tmp, 0);
  reduce_k<<<nRed, 256, 0, stream>>>(h1, tmp, nodeoff, plist, 0);
  gemm_edge<KP><<<gEdge, 256, 0, stream>>>(xp, wt1, es, enorm, offr, tmp, 1);
  reduce_k<<<nRed, 256, 0, stream>>>(h1, tmp, nodeoff, plist, 128);

  // Layer 2 (xp/wt1/wtr1 dead; h2 written by root)
  gemm_root<HD><<<gRoot, 256, 0, stream>>>(h1, wtr2, b2, h2, NN);
  gemm_edge<HD><<<gEdge, 256, 0, stream>>>(h1, wt2, es, enorm, offr, tmp, 0);
  reduce_k<<<nRed, 256, 0, stream>>>(h2, tmp, nodeoff, plist, 0);
  gemm_edge<HD><<<gEdge, 256, 0, stream>>>(h1, wt2, es, enorm, offr, tmp, 1);
  reduce_k<<<nRed, 256, 0, stream>>>(h2, tmp, nodeoff, plist, 128);

  // Pooling + MLP head
  pool_k<<<(NG * 64 + 255) / 256, 256, 0, stream>>>(h2, wsw, wsb, goff, g);
  mlp_k<<<NG, 64, 0, stream>>>(g, m1, mb1, m2, mb2, m3, mb3, outp);
}

// Round 9
// 546.801 us; speedup vs baseline: 4.4321x; 1.0758x over previous
//
#include <hip/hip_runtime.h>
#include <hip/hip_bf16.h>

// Problem constants
#define NN 50000
#define NE 150000
#define NR 65
#define NG 2000
#define FIN 74
#define KP 96      // layer-1 K padded (zero-filled)
#define HD 256
#define MH 64

#define TE2 128    // rows per GEMM tile
#define MAX_T2 20  // tile slots per relation (loop covers overflow)

#define EPB 1024                    // edges per sort block
#define NB ((NE + EPB - 1) / EPB)   // 147
#define NTOT (NR * NB)              // 9555

#define SCHUNK 512                  // elements per scan block

typedef __attribute__((ext_vector_type(8))) short bf16x8;
typedef __attribute__((ext_vector_type(4))) float f32x4;

__device__ __forceinline__ unsigned short f2bf(float x) {
  unsigned u = __builtin_bit_cast(unsigned, x);
  u += 0x7FFF + ((u >> 16) & 1);  // RNE
  return (unsigned short)(u >> 16);
}
__device__ __forceinline__ float bf2f(unsigned short h) {
  unsigned u = (unsigned)h << 16;
  return __builtin_bit_cast(float, u);
}

__device__ __forceinline__ void gl16(const short* g, short* lds) {
  __builtin_amdgcn_global_load_lds(
      (const __attribute__((address_space(1))) void*)g,
      (__attribute__((address_space(3))) void*)lds, 16, 0, 0);
}

// ---------------------------------------------------------------------------
// Weight prep: fp32 W[nmat][Kin][256] -> bf16 hi/lo planes, laid out as
// [mat][plane(hi,lo)][kstep][16 col-groups][1KB], MFMA stacked-K perm + XOR
// bank-swizzle baked in so GEMMs stage with linear global_load_lds.
// ---------------------------------------------------------------------------
__global__ void build_wt(const float* __restrict__ Wsrc, short* __restrict__ dst,
                         int Kin, int KC, int nmat) {
  int tid = blockIdx.x * 256 + threadIdx.x;
  int total = nmat * KC * 1024;
  if (tid >= total) return;
  int c = tid & 3;
  int colin = (tid >> 2) & 15;
  int grp = (tid >> 6) & 15;
  int rem = tid >> 10;
  int ks = rem % KC;
  int mat = rem / KC;
  int col = grp * 16 + colin;
  bf16x8 hv, lv;
#pragma unroll
  for (int i = 0; i < 8; ++i) {
    int kk = (i < 4) ? (c * 4 + i) : (16 + c * 4 + (i - 4));
    int k = ks * 32 + kk;
    float v = (k < Kin) ? Wsrc[((size_t)mat * Kin + k) * HD + col] : 0.f;
    unsigned short h = f2bf(v);
    hv[i] = (short)h;
    lv[i] = (short)f2bf(v - bf2f(h));
  }
  int slot = grp * 1024 + ((colin * 64 + c * 16) ^ ((colin & 7) << 4));
  size_t matbase = (size_t)mat * 2 * KC * 16384;
  *(bf16x8*)((char*)dst + matbase + (size_t)ks * 16384 + slot) = hv;
  *(bf16x8*)((char*)dst + matbase + (size_t)(KC + ks) * 16384 + slot) = lv;
}

// x [NN][74] -> xp [NN][96] zero-padded
__global__ void padx_k(const float* __restrict__ x, float* __restrict__ xp) {
  int i = blockIdx.x * 256 + threadIdx.x;
  if (i < NN * KP) {
    int n = i / KP, k = i - n * KP;
    xp[i] = (k < FIN) ? x[(size_t)n * FIN + k] : 0.f;
  }
}

// ---------------------------------------------------------------------------
// Edge preprocessing — contention-free counting sort by relation.
// ---------------------------------------------------------------------------
__global__ void count_k(const int* __restrict__ dst, const int* __restrict__ et,
                        int* __restrict__ cnt, int* __restrict__ ndeg) {
  int e = blockIdx.x * 256 + threadIdx.x;
  if (e < NE) {
    atomicAdd(&cnt[(size_t)dst[e] * NR + et[e]], 1);
    atomicAdd(&ndeg[dst[e]], 1);
  }
}

__global__ void gcount_k(const int* __restrict__ batch, int* __restrict__ ghist) {
  int i = blockIdx.x * 256 + threadIdx.x;
  if (i < NN) atomicAdd(&ghist[batch[i]], 1);
}

// Per-block relation histogram -> bh[r*NB + b]
__global__ __launch_bounds__(EPB) void histblk_k(const int* __restrict__ et,
                                                 int* __restrict__ bh) {
  __shared__ int lh[NR];
  int t = threadIdx.x, b = blockIdx.x;
  if (t < NR) lh[t] = 0;
  __syncthreads();
  int e = b * EPB + t;
  if (e < NE) atomicAdd(&lh[et[e]], 1);
  __syncthreads();
  if (t < NR) bh[t * NB + b] = lh[t];
}

// ---------------------------------------------------------------------------
// Hierarchical exclusive scan
// ---------------------------------------------------------------------------
__global__ __launch_bounds__(256) void psum_k(const int* __restrict__ in,
                                              int* __restrict__ bsum, int n) {
  __shared__ int ws4[4];
  int b = blockIdx.x, t = threadIdx.x;
  int base = b * SCHUNK;
  int s = 0;
#pragma unroll
  for (int i = 0; i < SCHUNK / 256; ++i) {
    int g = base + t + i * 256;
    if (g < n) s += in[g];
  }
#pragma unroll
  for (int o = 32; o > 0; o >>= 1) s += __shfl_down(s, o, 64);
  if ((t & 63) == 0) ws4[t >> 6] = s;
  __syncthreads();
  if (t == 0) bsum[b] = ws4[0] + ws4[1] + ws4[2] + ws4[3];
}

__global__ __launch_bounds__(256) void scanb_k(int* __restrict__ bsum, int nb) {
  __shared__ int ld[256];
  int t = threadIdx.x;
  int v = (t < nb) ? bsum[t] : 0;
  ld[t] = v;
  __syncthreads();
  int acc = v;
#pragma unroll
  for (int o = 1; o < 256; o <<= 1) {
    int u = (t >= o) ? ld[t - o] : 0;
    __syncthreads();
    acc += u;
    ld[t] = acc;
    __syncthreads();
  }
  if (t < nb) bsum[t] = acc - v;
  if (t == nb - 1) bsum[nb] = acc;
}

__global__ __launch_bounds__(256) void apply_k(const int* __restrict__ in,
                                               const int* __restrict__ bsum,
                                               int* __restrict__ out, int n) {
  __shared__ int ld[256];
  int b = blockIdx.x, t = threadIdx.x;
  int base = b * SCHUNK + t * 2;
  int v0 = (base < n) ? in[base] : 0;
  int v1 = (base + 1 < n) ? in[base + 1] : 0;
  int ps = v0 + v1;
  ld[t] = ps;
  __syncthreads();
  int acc = ps;
#pragma unroll
  for (int o = 1; o < 256; o <<= 1) {
    int u = (t >= o) ? ld[t - o] : 0;
    __syncthreads();
    acc += u;
    ld[t] = acc;
    __syncthreads();
  }
  int excl = acc - ps + bsum[b];
  if (base < n) out[base] = excl;
  if (base + 1 < n) out[base + 1] = excl + v0;
  if (base == n - 1) out[n] = excl + v0;
  else if (base + 1 == n - 1) out[n] = excl + v0 + v1;
}

__global__ void offr_k(const int* __restrict__ start, int* __restrict__ offr) {
  int t = threadIdx.x;
  if (t < NR) offr[t] = start[t * NB];
  if (t == NR) offr[NR] = start[NTOT];
}

__global__ __launch_bounds__(EPB) void place_k(const int* __restrict__ src,
                                               const int* __restrict__ dst,
                                               const int* __restrict__ et,
                                               const int* __restrict__ cnt,
                                               const int* __restrict__ start,
                                               int* __restrict__ es,
                                               int* __restrict__ ed,
                                               float* __restrict__ enorm) {
  __shared__ int lcur[NR];
  int t = threadIdx.x, b = blockIdx.x;
  if (t < NR) lcur[t] = 0;
  __syncthreads();
  int e = b * EPB + t;
  if (e < NE) {
    int r = et[e];
    int d = dst[e];
    int rank = atomicAdd(&lcur[r], 1);
    int p = start[r * NB + b] + rank;
    es[p] = src[e];
    ed[p] = d;
    int c = cnt[(size_t)d * NR + r];
    enorm[p] = 1.0f / (float)(c > 0 ? c : 1);
  }
}

__global__ void plist_k(const int* __restrict__ ed, const int* __restrict__ nodeoff,
                        int* __restrict__ ncur, int* __restrict__ plist) {
  int p = blockIdx.x * 256 + threadIdx.x;
  if (p < NE) {
    int d = ed[p];
    int q = nodeoff[d] + atomicAdd(&ncur[d], 1);
    plist[q] = p;
  }
}

// ---------------------------------------------------------------------------
// MFMA GEMM core, merged full-width: 128 rows x 256 cols, 512 thr (8 waves
// as 2 row x 4 col), each wave 4x4 frags of 16x16x32 bf16, split bf16x2.
// LDS 48KB: A hi/lo 2x8KB + B hi/lo 2x16KB.
// ---------------------------------------------------------------------------
#define MFMA_BF16 __builtin_amdgcn_mfma_f32_16x16x32_bf16

template<int K>
__global__ __launch_bounds__(512) void gemm_edge(const float* __restrict__ X,
                                                 const short* __restrict__ Wt,
                                                 const int* __restrict__ es,
                                                 const float* __restrict__ enorm,
                                                 const int* __restrict__ offr,
                                                 unsigned short* __restrict__ tmp) {
  constexpr int KC = K / 32;
  __shared__ __align__(16) short Ah[4096], Al[4096], Bh[8192], Bl[8192];
  const int t = threadIdx.x;
  const int rel = blockIdx.x / MAX_T2;
  const int tile = blockIdx.x % MAX_T2;
  const int e_lo = offr[rel], e_hi = offr[rel + 1];
  if (e_lo + tile * TE2 >= e_hi) return;
  const short* WtM = Wt + (size_t)rel * (2 * KC * 8192);
  const int lane = t & 63, w = t >> 6;
  const int r = t & 127, c = t >> 7;           // staging: row, c-group (0..3)
  const int rowg = (w & 1) * 4;                // A row-group base (16-row units)
  const int colg = (w >> 1) * 4;               // B col-group base (16-col units)
  const int fo = (((lane & 15) * 64 + (lane >> 4) * 16) ^ ((lane & 7) << 4)) >> 1;

  for (int base = e_lo + tile * TE2; base < e_hi; base += MAX_T2 * TE2) {
    const int nE = min(TE2, e_hi - base);
    const float* xrow = X + (size_t)es[base + ((r < nE) ? r : 0)] * K;
    const float nrm = (r < nE) ? enorm[base + r] : 0.f;
    f32x4 acc[4][4];
#pragma unroll
    for (int f = 0; f < 4; ++f)
#pragma unroll
      for (int n = 0; n < 4; ++n) acc[f][n] = {0.f, 0.f, 0.f, 0.f};

    for (int ks = 0; ks < KC; ++ks) {
      // B: 32KB via DMA; wave w stages chunks w*2, w*2+1 of each plane
#pragma unroll
      for (int j = 0; j < 2; ++j) {
        int ch = w * 2 + j;
        gl16(WtM + (size_t)ks * 8192 + ch * 512 + lane * 8, &Bh[ch * 512]);
        gl16(WtM + (size_t)(KC + ks) * 8192 + ch * 512 + lane * 8, &Bl[ch * 512]);
      }
      // A: gather + norm + split + swizzled ds_write_b128 (one c-group/thread)
      {
        float4 a = *(const float4*)&xrow[ks * 32 + c * 4];
        float4 b = *(const float4*)&xrow[ks * 32 + 16 + c * 4];
        float v[8] = {a.x * nrm, a.y * nrm, a.z * nrm, a.w * nrm,
                      b.x * nrm, b.y * nrm, b.z * nrm, b.w * nrm};
        bf16x8 hv, lv;
#pragma unroll
        for (int i = 0; i < 8; ++i) {
          unsigned short h = f2bf(v[i]);
          hv[i] = (short)h;
          lv[i] = (short)f2bf(v[i] - bf2f(h));
        }
        int ab = (r * 64 + c * 16) ^ ((r & 7) << 4);
        *(bf16x8*)((char*)Ah + ab) = hv;
        *(bf16x8*)((char*)Al + ab) = lv;
      }
      __syncthreads();
      bf16x8 afh[4], afl[4], bfh[4], bfl[4];
#pragma unroll
      for (int f = 0; f < 4; ++f) {
        int o = (rowg + f) * 512 + fo;
        afh[f] = *(const bf16x8*)&Ah[o];
        afl[f] = *(const bf16x8*)&Al[o];
      }
#pragma unroll
      for (int n = 0; n < 4; ++n) {
        int o = (colg + n) * 512 + fo;
        bfh[n] = *(const bf16x8*)&Bh[o];
        bfl[n] = *(const bf16x8*)&Bl[o];
      }
#pragma unroll
      for (int f = 0; f < 4; ++f)
#pragma unroll
        for (int n = 0; n < 4; ++n) {
          acc[f][n] = MFMA_BF16(afh[f], bfh[n], acc[f][n], 0, 0, 0);
          acc[f][n] = MFMA_BF16(afh[f], bfl[n], acc[f][n], 0, 0, 0);
          acc[f][n] = MFMA_BF16(afl[f], bfh[n], acc[f][n], 0, 0, 0);
        }
      __syncthreads();
    }
    // D layout: row=(lane>>4)*4+reg, col=lane&15 (verified m89/m91); bf16 store
#pragma unroll
    for (int f = 0; f < 4; ++f) {
      int rb = (rowg + f) * 16 + (lane >> 4) * 4;
#pragma unroll
      for (int rr = 0; rr < 4; ++rr) {
        int row = rb + rr;
        if (row < nE) {
          unsigned short* o = &tmp[(size_t)(base + row) * HD + colg * 16 + (lane & 15)];
#pragma unroll
          for (int n = 0; n < 4; ++n) o[n * 16] = f2bf(acc[f][n][rr]);
        }
      }
    }
  }
}

template<int K>
__global__ __launch_bounds__(512) void gemm_root(const float* __restrict__ X,
                                                 const short* __restrict__ Wtr,
                                                 const float* __restrict__ bias,
                                                 float* __restrict__ out, int M) {
  constexpr int KC = K / 32;
  __shared__ __align__(16) short Ah[4096], Al[4096], Bh[8192], Bl[8192];
  const int t = threadIdx.x;
  const int row0 = blockIdx.x * TE2;
  const int lane = t & 63, w = t >> 6;
  const int r = t & 127, c = t >> 7;
  const int rowg = (w & 1) * 4;
  const int colg = (w >> 1) * 4;
  const int fo = (((lane & 15) * 64 + (lane >> 4) * 16) ^ ((lane & 7) << 4)) >> 1;

  const int gr = row0 + r;
  const float* xrow = X + (size_t)(gr < M ? gr : 0) * K;
  const float nrm = (gr < M) ? 1.f : 0.f;
  f32x4 acc[4][4];
#pragma unroll
  for (int f = 0; f < 4; ++f)
#pragma unroll
    for (int n = 0; n < 4; ++n) acc[f][n] = {0.f, 0.f, 0.f, 0.f};

  for (int ks = 0; ks < KC; ++ks) {
#pragma unroll
    for (int j = 0; j < 2; ++j) {
      int ch = w * 2 + j;
      gl16(Wtr + (size_t)ks * 8192 + ch * 512 + lane * 8, &Bh[ch * 512]);
      gl16(Wtr + (size_t)(KC + ks) * 8192 + ch * 512 + lane * 8, &Bl[ch * 512]);
    }
    {
      float4 a = *(const float4*)&xrow[ks * 32 + c * 4];
      float4 b = *(const float4*)&xrow[ks * 32 + 16 + c * 4];
      float v[8] = {a.x * nrm, a.y * nrm, a.z * nrm, a.w * nrm,
                    b.x * nrm, b.y * nrm, b.z * nrm, b.w * nrm};
      bf16x8 hv, lv;
#pragma unroll
      for (int i = 0; i < 8; ++i) {
        unsigned short h = f2bf(v[i]);
        hv[i] = (short)h;
        lv[i] = (short)f2bf(v[i] - bf2f(h));
      }
      int ab = (r * 64 + c * 16) ^ ((r & 7) << 4);
      *(bf16x8*)((char*)Ah + ab) = hv;
      *(bf16x8*)((char*)Al + ab) = lv;
    }
    __syncthreads();
    bf16x8 afh[4], afl[4], bfh[4], bfl[4];
#pragma unroll
    for (int f = 0; f < 4; ++f) {
      int o = (rowg + f) * 512 + fo;
      afh[f] = *(const bf16x8*)&Ah[o];
      afl[f] = *(const bf16x8*)&Al[o];
    }
#pragma unroll
    for (int n = 0; n < 4; ++n) {
      int o = (colg + n) * 512 + fo;
      bfh[n] = *(const bf16x8*)&Bh[o];
      bfl[n] = *(const bf16x8*)&Bl[o];
    }
#pragma unroll
    for (int f = 0; f < 4; ++f)
#pragma unroll
      for (int n = 0; n < 4; ++n) {
        acc[f][n] = MFMA_BF16(afh[f], bfh[n], acc[f][n], 0, 0, 0);
        acc[f][n] = MFMA_BF16(afh[f], bfl[n], acc[f][n], 0, 0, 0);
        acc[f][n] = MFMA_BF16(afl[f], bfh[n], acc[f][n], 0, 0, 0);
      }
    __syncthreads();
  }
#pragma unroll
  for (int f = 0; f < 4; ++f) {
    int rb = (rowg + f) * 16 + (lane >> 4) * 4;
#pragma unroll
    for (int rr = 0; rr < 4; ++rr) {
      int row = rb + rr;
      if (row0 + row < M) {
#pragma unroll
        for (int n = 0; n < 4; ++n) {
          int cg = (colg + n) * 16 + (lane & 15);
          out[(size_t)(row0 + row) * HD + cg] = acc[f][n][rr] + bias[cg];
        }
      }
    }
  }
}

// ---------------------------------------------------------------------------
// Per-node gather-reduce, full width: h[n] = relu(h[n] + sum bf16 tmp rows)
// ---------------------------------------------------------------------------
__global__ __launch_bounds__(256) void reduce_k(float* __restrict__ h,
                                                const unsigned short* __restrict__ tmp,
                                                const int* __restrict__ nodeoff,
                                                const int* __restrict__ plist) {
  int wid = (blockIdx.x * 256 + threadIdx.x) >> 6;
  int lane = threadIdx.x & 63;
  if (wid >= NN) return;
  float* row = h + (size_t)wid * HD + lane * 4;
  float4 acc = *(float4*)row;
  int lo = nodeoff[wid], hi = nodeoff[wid + 1];
  for (int q = lo; q < hi; ++q) {
    int p = plist[q];
    ushort4 m = *(const ushort4*)&tmp[(size_t)p * HD + lane * 4];
    acc.x += bf2f(m.x);
    acc.y += bf2f(m.y);
    acc.z += bf2f(m.z);
    acc.w += bf2f(m.w);
  }
  acc.x = fmaxf(acc.x, 0.f);
  acc.y = fmaxf(acc.y, 0.f);
  acc.z = fmaxf(acc.z, 0.f);
  acc.w = fmaxf(acc.w, 0.f);
  *(float4*)row = acc;
}

// ---------------------------------------------------------------------------
// Pooling and fused MLP head
// ---------------------------------------------------------------------------
__global__ __launch_bounds__(256) void pool_k(const float* __restrict__ h,
                                              const float* __restrict__ wsw,
                                              const float* __restrict__ wsb,
                                              const int* __restrict__ goff,
                                              float* __restrict__ g) {
  int wid = (blockIdx.x * 256 + threadIdx.x) >> 6;
  int lane = threadIdx.x & 63;
  if (wid >= NG) return;
  float4 w4 = *(const float4*)&wsw[lane * 4];
  float wb = wsb[0];
  float4 acc = make_float4(0.f, 0.f, 0.f, 0.f);
  int lo = goff[wid], hi = goff[wid + 1];
  for (int n = lo; n < hi; ++n) {
    float4 v = *(const float4*)&h[(size_t)n * HD + lane * 4];
    float p = v.x * w4.x + v.y * w4.y + v.z * w4.z + v.w * w4.w;
#pragma unroll
    for (int o = 32; o > 0; o >>= 1) p += __shfl_xor(p, o, 64);
    float gate = 1.f / (1.f + expf(-(p + wb)));
    acc.x += gate * v.x;
    acc.y += gate * v.y;
    acc.z += gate * v.z;
    acc.w += gate * v.w;
  }
  *(float4*)&g[(size_t)wid * HD + lane * 4] = acc;
}

__global__ __launch_bounds__(64) void mlp_k(const float* __restrict__ g,
                                            const float* __restrict__ m1,
                                            const float* __restrict__ mb1,
                                            const float* __restrict__ m2,
                                            const float* __restrict__ mb2,
                                            const float* __restrict__ m3,
                                            const float* __restrict__ mb3,
                                            float* __restrict__ out) {
  __shared__ float sg[HD];
  __shared__ float s1[MH];
  int gr = blockIdx.x;
  int t = threadIdx.x;
  float4 v = *(const float4*)&g[(size_t)gr * HD + t * 4];
  *(float4*)&sg[t * 4] = v;
  __syncthreads();
  float a = mb1[t];
  for (int k = 0; k < HD; ++k) a += sg[k] * m1[k * MH + t];
  a = fmaxf(a, 0.f);
  s1[t] = a;
  __syncthreads();
  float b = mb2[t];
#pragma unroll
  for (int k = 0; k < MH; ++k) b += s1[k] * m2[k * MH + t];
  b = fmaxf(b, 0.f);
  float c = b * m3[t];
#pragma unroll
  for (int o = 32; o > 0; o >>= 1) c += __shfl_xor(c, o, 64);
  if (t == 0) out[gr] = c + mb3[0];
}

// ---------------------------------------------------------------------------
extern "C" void kernel_launch(void* const* d_in, const int* in_sizes, int n_in,
                              void* d_out, int out_size, void* d_ws, size_t ws_size,
                              hipStream_t stream) {
  const float* x = (const float*)d_in[0];
  const int* ei = (const int*)d_in[1];
  const int* etype = (const int*)d_in[2];
  const int* batch = (const int*)d_in[3];
  const float* W1 = (const float*)d_in[4];
  const float* root1 = (const float*)d_in[5];
  const float* b1 = (const float*)d_in[6];
  const float* W2 = (const float*)d_in[7];
  const float* root2 = (const float*)d_in[8];
  const float* b2 = (const float*)d_in[9];
  const float* wsw = (const float*)d_in[10];
  const float* wsb = (const float*)d_in[11];
  const float* m1 = (const float*)d_in[12];
  const float* mb1 = (const float*)d_in[13];
  const float* m2 = (const float*)d_in[14];
  const float* mb2 = (const float*)d_in[15];
  const float* m3 = (const float*)d_in[16];
  const float* mb3 = (const float*)d_in[17];
  const int* esrc = ei;
  const int* edst = ei + NE;

  constexpr int KC1 = KP / 32;  // 3
  constexpr int KC2 = HD / 32;  // 8
  const int nbN = (NN + SCHUNK - 1) / SCHUNK;
  const int nbT = (NTOT + SCHUNK - 1) / SCHUNK;
  const int nbG = (NG + SCHUNK - 1) / SCHUNK;

  // Workspace layout (256B aligned). Aliases:
  //   cnt (NN*NR ints)   over tmp head (dead before tmp written)
  //   xp / wt1 / wtr1    inside h2     (dead before L2 root writes h2)
  char* ws = (char*)d_ws;
  size_t off = 0;
  auto alloc = [&](size_t bytes) {
    size_t o = off;
    off = (off + bytes + 255) & ~(size_t)255;
    return o;
  };
  size_t o_tmp = alloc((size_t)NE * HD * 2);       // 76.8 MB (bf16, full width)
  size_t o_h1 = alloc((size_t)NN * HD * 4);        // 51.2 MB
  size_t o_h2x = alloc((size_t)NN * HD * 4);       // 51.2 MB (h2 | xp+wt1+wtr1)
  size_t o_g = alloc((size_t)NG * HD * 4);
  size_t o_es = alloc((size_t)NE * 4);
  size_t o_ed = alloc((size_t)NE * 4);
  size_t o_enorm = alloc((size_t)NE * 4);
  size_t o_plist = alloc((size_t)NE * 4);
  size_t o_nodeoff = alloc((NN + 1) * 4);
  size_t o_goff = alloc((NG + 1) * 4);
  size_t o_offr = alloc((NR + 1) * 4);
  size_t o_bh = alloc((size_t)NTOT * 4);
  size_t o_start = alloc((size_t)(NTOT + 1) * 4);
  size_t o_bsN = alloc((size_t)(nbN + 1) * 4);
  size_t o_bsT = alloc((size_t)(nbT + 1) * 4);
  size_t o_bsG = alloc((size_t)(nbG + 1) * 4);
  size_t o_wt2 = alloc((size_t)NR * 2 * KC2 * 16384);  // 17.04 MB
  size_t o_wtr2 = alloc((size_t)2 * KC2 * 16384);      // 262 KB
  size_t zs = off;  // zero region
  size_t o_ndeg = alloc((size_t)NN * 4);
  size_t o_ncur = alloc((size_t)NN * 4);
  size_t o_ghist = alloc((size_t)NG * 4);
  size_t ze = off;
  if (ws_size < off) return;

  unsigned short* tmp = (unsigned short*)(ws + o_tmp);
  int* cnt = (int*)(ws + o_tmp);                   // alias (13 MB < 76.8 MB)
  float* h1 = (float*)(ws + o_h1);
  float* h2 = (float*)(ws + o_h2x);
  float* xp = (float*)(ws + o_h2x);                // alias (19.2 MB)
  short* wt1 = (short*)(ws + o_h2x + 19200000);    // alias (6.39 MB)
  short* wtr1 = (short*)(ws + o_h2x + 19200000 + 6389760);  // alias (98 KB)
  float* g = (float*)(ws + o_g);
  int* es = (int*)(ws + o_es);
  int* ed = (int*)(ws + o_ed);
  float* enorm = (float*)(ws + o_enorm);
  int* plist = (int*)(ws + o_plist);
  int* nodeoff = (int*)(ws + o_nodeoff);
  int* goff = (int*)(ws + o_goff);
  int* offr = (int*)(ws + o_offr);
  int* bh = (int*)(ws + o_bh);
  int* start = (int*)(ws + o_start);
  int* bsN = (int*)(ws + o_bsN);
  int* bsT = (int*)(ws + o_bsT);
  int* bsG = (int*)(ws + o_bsG);
  short* wt2 = (short*)(ws + o_wt2);
  short* wtr2 = (short*)(ws + o_wtr2);
  int* ndeg = (int*)(ws + o_ndeg);
  int* ncur = (int*)(ws + o_ncur);
  int* ghist = (int*)(ws + o_ghist);
  float* outp = (float*)d_out;

  hipMemsetAsync(ws + o_tmp, 0, (size_t)NN * NR * 4, stream);  // cnt
  hipMemsetAsync(ws + zs, 0, ze - zs, stream);

  // Weight prep + padded x
  padx_k<<<(NN * KP + 255) / 256, 256, 0, stream>>>(x, xp);
  build_wt<<<(NR * KC1 * 1024 + 255) / 256, 256, 0, stream>>>(W1, wt1, FIN, KC1, NR);
  build_wt<<<(KC1 * 1024 + 255) / 256, 256, 0, stream>>>(root1, wtr1, FIN, KC1, 1);
  build_wt<<<(NR * KC2 * 1024 + 255) / 256, 256, 0, stream>>>(W2, wt2, HD, KC2, NR);
  build_wt<<<(KC2 * 1024 + 255) / 256, 256, 0, stream>>>(root2, wtr2, HD, KC2, 1);

  // Edge preprocessing — contention-free sort + hierarchical scans
  count_k<<<(NE + 255) / 256, 256, 0, stream>>>(edst, etype, cnt, ndeg);
  gcount_k<<<(NN + 255) / 256, 256, 0, stream>>>(batch, ghist);
  histblk_k<<<NB, EPB, 0, stream>>>(etype, bh);

  psum_k<<<nbT, 256, 0, stream>>>(bh, bsT, NTOT);
  scanb_k<<<1, 256, 0, stream>>>(bsT, nbT);
  apply_k<<<nbT, 256, 0, stream>>>(bh, bsT, start, NTOT);
  offr_k<<<1, 128, 0, stream>>>(start, offr);

  psum_k<<<nbN, 256, 0, stream>>>(ndeg, bsN, NN);
  scanb_k<<<1, 256, 0, stream>>>(bsN, nbN);
  apply_k<<<nbN, 256, 0, stream>>>(ndeg, bsN, nodeoff, NN);

  psum_k<<<nbG, 256, 0, stream>>>(ghist, bsG, NG);
  scanb_k<<<1, 256, 0, stream>>>(bsG, nbG);
  apply_k<<<nbG, 256, 0, stream>>>(ghist, bsG, goff, NG);

  place_k<<<NB, EPB, 0, stream>>>(esrc, edst, etype, cnt, start, es, ed, enorm);
  plist_k<<<(NE + 255) / 256, 256, 0, stream>>>(ed, nodeoff, ncur, plist);

  const int gRoot = (NN + TE2 - 1) / TE2;
  const int gEdge = NR * MAX_T2;
  const int nRed = (NN * 64 + 255) / 256;

  // Layer 1
  gemm_root<KP><<<gRoot, 512, 0, stream>>>(xp, wtr1, b1, h1, NN);
  gemm_edge<KP><<<gEdge, 512, 0, stream>>>(xp, wt1, es, enorm, offr, tmp);
  reduce_k<<<nRed, 256, 0, stream>>>(h1, tmp, nodeoff, plist);

  // Layer 2 (xp/wt1/wtr1 dead; h2 written by root)
  gemm_root<HD><<<gRoot, 512, 0, stream>>>(h1, wtr2, b2, h2, NN);
  gemm_edge<HD><<<gEdge, 512, 0, stream>>>(h1, wt2, es, enorm, offr, tmp);
  reduce_k<<<nRed, 256, 0, stream>>>(h2, tmp, nodeoff, plist);

  // Pooling + MLP head
  pool_k<<<(NG * 64 + 255) / 256, 256, 0, stream>>>(h2, wsw, wsb, goff, g);
  mlp_k<<<NG, 64, 0, stream>>>(g, m1, mb1, m2, mb2, m3, mb3, outp);
}